// Round 7
// baseline (571.820 us; speedup 1.0000x reference)
//
#include <hip/hip_runtime.h>
#include <hip/hip_bf16.h>
#include <hip/hip_fp16.h>

#define D_IN  128
#define D_HID 16
#define N_CLS 2
#define NPB   256          // nodes per bucket (bucket = dst >> 8)
#define MAXB  512          // max buckets (N <= 131072)
#define TILE  8192         // edges per k_part workgroup

#define FE 0   // edge_index storage: 0 = int32, 1 = int64

// ---------------- edge dtype detection (1 block) ----------------
__global__ void k_detect(const int* __restrict__ ev, int* __restrict__ flags) {
    __shared__ int sE;
    if (threadIdx.x == 0) sE = 0;
    __syncthreads();
    if (ev[2 * threadIdx.x + 1] != 0) atomicOr(&sE, 1);
    __syncthreads();
    if (threadIdx.x == 0) flags[FE] = sE ? 0 : 1;
}

template<bool I64>
__device__ __forceinline__ int lde(const void* p, size_t i) {
    if constexpr (I64) return (int)((const long long*)p)[i];
    else               return ((const int*)p)[i];
}

// ---------------- bucket histogram (LDS-privatized, grid-stride) ----------------
template<bool I64>
__global__ void k_bhist(const void* __restrict__ ei, unsigned int* __restrict__ gbcnt,
                        int E, const int* __restrict__ flags) {
    if (flags[FE] != (int)I64) return;
    __shared__ unsigned int h[MAXB];
    for (int i = threadIdx.x; i < MAXB; i += blockDim.x) h[i] = 0u;
    __syncthreads();
    int stride = gridDim.x * blockDim.x;
    for (int e = blockIdx.x * blockDim.x + threadIdx.x; e < E; e += stride) {
        int d = lde<I64>(ei, (size_t)E + e);
        atomicAdd(&h[d >> 8], 1u);
    }
    __syncthreads();
    for (int i = threadIdx.x; i < MAXB; i += blockDim.x)
        if (h[i]) atomicAdd(&gbcnt[i], h[i]);
}

// ---------------- bucket scan: bbase (exclusive) + cursor init ----------------
__global__ void k_bscan(const unsigned int* __restrict__ gbcnt, int* __restrict__ bbase,
                        unsigned int* __restrict__ gcur, int nb) {
    __shared__ int s[MAXB];
    int tid = threadIdx.x;
    int v = (tid < nb) ? (int)gbcnt[tid] : 0;
    s[tid] = v;
    __syncthreads();
#pragma unroll
    for (int off = 1; off < MAXB; off <<= 1) {
        int t = (tid >= off) ? s[tid - off] : 0;
        __syncthreads();
        s[tid] += t;
        __syncthreads();
    }
    int excl = s[tid] - v;
    if (tid <= nb) bbase[tid] = (tid < nb) ? excl : s[nb - 1];  // bbase[nb] = total
    if (tid < nb)  gcur[tid] = (unsigned int)excl;
}

// ---------------- pass 1: LDS-staged partition by bucket ----------------
template<bool I64>
__global__ __launch_bounds__(512) void k_part(
        const void* __restrict__ ei, unsigned int* __restrict__ gcur,
        unsigned int* __restrict__ staged, int E, const int* __restrict__ flags) {
    if (flags[FE] != (int)I64) return;
    __shared__ unsigned int sbuf[TILE];       // 32 KB packed values
    __shared__ unsigned short bbuf[TILE];     // 16 KB bucket ids
    __shared__ int hist[MAXB], scn[MAXB], lbase[MAXB], gb[MAXB];  // 8 KB
    int tid = threadIdx.x;
    int t0 = blockIdx.x * TILE;

    hist[tid] = 0;
    __syncthreads();

    int myB[16]; unsigned int myP[16]; int myR[16];
#pragma unroll
    for (int k = 0; k < 16; ++k) {
        int e = t0 + k * 512 + tid;
        if (e < E) {
            int s = lde<I64>(ei, (size_t)e);
            int d = lde<I64>(ei, (size_t)E + e);
            int b = d >> 8;
            myB[k] = b;
            myP[k] = ((unsigned int)s << 8) | (unsigned int)(d & 255);
            myR[k] = atomicAdd(&hist[b], 1);
        } else myB[k] = -1;
    }
    __syncthreads();

    int v = hist[tid];
    scn[tid] = v;
    __syncthreads();
#pragma unroll
    for (int off = 1; off < MAXB; off <<= 1) {
        int t = (tid >= off) ? scn[tid - off] : 0;
        __syncthreads();
        scn[tid] += t;
        __syncthreads();
    }
    int excl = scn[tid] - v;
    lbase[tid] = excl;
    int gb_ = 0;
    if (v > 0) gb_ = (int)atomicAdd(&gcur[tid], (unsigned int)v);
    gb[tid] = gb_;
    __syncthreads();

#pragma unroll
    for (int k = 0; k < 16; ++k) {
        if (myB[k] >= 0) {
            int pos = lbase[myB[k]] + myR[k];
            sbuf[pos] = myP[k];
            bbuf[pos] = (unsigned short)myB[k];
        }
    }
    __syncthreads();

    int tot = scn[MAXB - 1];
    for (int i = tid; i < tot; i += 512) {
        int b = bbuf[i];
        staged[(size_t)gb[b] + (i - lbase[b])] = sbuf[i];  // ~84B contiguous runs
    }
}

// ---------------- per-bucket degree -> dinv ----------------
__global__ __launch_bounds__(512) void k_dinv2(
        const unsigned int* __restrict__ staged, const int* __restrict__ bbase,
        float* __restrict__ dinv, int N) {
    __shared__ unsigned int h[NPB];
    int tid = threadIdx.x, b = blockIdx.x;
    int s0 = bbase[b], cnt = bbase[b + 1] - s0;
    if (tid < NPB) h[tid] = 0u;
    __syncthreads();
    for (int j = tid; j < cnt; j += 512)
        atomicAdd(&h[staged[(size_t)s0 + j] & 255], 1u);
    __syncthreads();
    int base = b * NPB, nn = N - base; if (nn > NPB) nn = NPB;
    if (tid < nn) dinv[base + tid] = rsqrtf((float)(h[tid] + 1u));  // +1 self loop
}

// ---------------- layer 1 GEMM: g1h = (half)(dinv * (x @ W1)) ----------------
__global__ void k_gemm1h(const float* __restrict__ x, const float* __restrict__ W1,
                         const float* __restrict__ dinv, __half* __restrict__ g1h, int n) {
    __shared__ float w[D_IN * D_HID];  // 8 KiB
    for (int i = threadIdx.x; i < D_IN * D_HID; i += blockDim.x)
        w[i] = W1[i];
    __syncthreads();
    int tid = blockIdx.x * blockDim.x + threadIdx.x;
    int node = tid >> 4, f = tid & 15;
    if (node >= n) return;
    const float4* xr = (const float4*)(x + (size_t)node * D_IN);
    float acc = 0.f;
#pragma unroll
    for (int k4 = 0; k4 < D_IN / 4; ++k4) {
        float4 v = xr[k4];
        int k = k4 * 4;
        acc += v.x * w[(k + 0) * D_HID + f];
        acc += v.y * w[(k + 1) * D_HID + f];
        acc += v.z * w[(k + 2) * D_HID + f];
        acc += v.w * w[(k + 3) * D_HID + f];
    }
    g1h[tid] = __float2half(dinv[node] * acc);
}

// ---------------- bucket-major agg1 + bias + ReLU + GEMM2 -> g2 ----------------
// One wg per bucket; a1 accumulated in LDS via float atomics (16 lanes/edge).
__global__ __launch_bounds__(1024) void k_agg1b(
        const unsigned int* __restrict__ staged, const int* __restrict__ bbase,
        const __half* __restrict__ g1h, const float* __restrict__ dinv,
        const float* __restrict__ b1, const float* __restrict__ W2,
        float2* __restrict__ g2, int N) {
    __shared__ float a1l[NPB * D_HID];   // 16 KB
    int tid = threadIdx.x, b = blockIdx.x;
    int s0 = bbase[b], cnt = bbase[b + 1] - s0;
    int base = b * NPB;
    for (int i = tid; i < NPB * D_HID; i += 1024) a1l[i] = 0.f;
    __syncthreads();
    int f = tid & 15;
#pragma unroll 2
    for (int j = tid >> 4; j < cnt; j += 64) {
        unsigned int p = staged[(size_t)s0 + j];   // same-address broadcast per 16 lanes
        int s = (int)(p >> 8), dl = (int)(p & 255);
        float v = __half2float(g1h[(size_t)s * D_HID + f]);
        atomicAdd(&a1l[dl * D_HID + f], v);
    }
    __syncthreads();
    int nn = N - base; if (nn > NPB) nn = NPB;
    for (int n = tid >> 4; n < nn; n += 64) {
        int gn = base + n;
        float acc = a1l[n * D_HID + f] + __half2float(g1h[(size_t)gn * D_HID + f]); // + self
        float di = dinv[gn];
        float r = fmaxf(b1[f] + di * acc, 0.f);
        float c0 = r * W2[f * N_CLS + 0];
        float c1 = r * W2[f * N_CLS + 1];
#pragma unroll
        for (int m = 8; m >= 1; m >>= 1) {
            c0 += __shfl_xor(c0, m, 64);
            c1 += __shfl_xor(c1, m, 64);
        }
        if (f == 0) g2[gn] = make_float2(di * c0, di * c1);
    }
}

// ---------------- bucket-major agg2 + bias + log_softmax -> out ----------------
__global__ __launch_bounds__(512) void k_agg2b(
        const unsigned int* __restrict__ staged, const int* __restrict__ bbase,
        const float2* __restrict__ g2, const float* __restrict__ dinv,
        const float* __restrict__ b2, float2* __restrict__ out, int N) {
    __shared__ float a2l[NPB * 2];   // 2 KB
    int tid = threadIdx.x, b = blockIdx.x;
    int s0 = bbase[b], cnt = bbase[b + 1] - s0;
    int base = b * NPB;
    for (int i = tid; i < NPB * 2; i += 512) a2l[i] = 0.f;
    __syncthreads();
    for (int j = tid; j < cnt; j += 512) {
        unsigned int p = staged[(size_t)s0 + j];
        int s = (int)(p >> 8), dl = (int)(p & 255);
        float2 t = g2[s];
        atomicAdd(&a2l[dl * 2 + 0], t.x);
        atomicAdd(&a2l[dl * 2 + 1], t.y);
    }
    __syncthreads();
    int nn = N - base; if (nn > NPB) nn = NPB;
    for (int n = tid; n < nn; n += 512) {
        int gn = base + n;
        float2 self = g2[gn];
        float di = dinv[gn];
        float v0 = b2[0] + di * (a2l[n * 2 + 0] + self.x);
        float v1 = b2[1] + di * (a2l[n * 2 + 1] + self.y);
        float mx = fmaxf(v0, v1);
        float lse = mx + logf(expf(v0 - mx) + expf(v1 - mx));
        out[gn] = make_float2(v0 - lse, v1 - lse);
    }
}

// =================== fallback (round-3 atomic path, if ws too small) ===================
__global__ void fb_deg_init(unsigned int* __restrict__ deg, int n) {
    int i = blockIdx.x * blockDim.x + threadIdx.x;
    if (i < n) deg[i] = 1u;
}
template<bool I64>
__global__ void fb_deg_count(const void* __restrict__ ei, unsigned int* __restrict__ deg,
                             int E, const int* __restrict__ flags) {
    if (flags[FE] != (int)I64) return;
    int e = blockIdx.x * blockDim.x + threadIdx.x;
    if (e < E) atomicAdd(&deg[lde<I64>(ei, (size_t)E + e)], 1u);
}
__global__ void fb_dinv_inplace(float* __restrict__ dinv, int n) {
    int i = blockIdx.x * blockDim.x + threadIdx.x;
    if (i < n) {
        unsigned int u = ((const unsigned int*)dinv)[i];
        dinv[i] = rsqrtf((float)u);
    }
}
__global__ void fb_a1_init(const float* __restrict__ h1, const float* __restrict__ dinv,
                           const float* __restrict__ b1, float* __restrict__ a1, int n) {
    int tid = blockIdx.x * blockDim.x + threadIdx.x;
    if (tid >= n * D_HID) return;
    int node = tid >> 4, f = tid & 15;
    float di = dinv[node];
    a1[tid] = b1[f] + di * di * h1[tid];
}
template<bool I64>
__global__ void fb_agg1(const void* __restrict__ ei, const float* __restrict__ dinv,
                        const float* __restrict__ h1, float* __restrict__ a1,
                        int E, const int* __restrict__ flags) {
    if (flags[FE] != (int)I64) return;
    int tid = blockIdx.x * blockDim.x + threadIdx.x;
    int e = tid >> 4, f = tid & 15;
    if (e >= E) return;
    int s = lde<I64>(ei, (size_t)e);
    int d = lde<I64>(ei, (size_t)E + e);
    float norm = dinv[s] * dinv[d];
    atomicAdd(&a1[(size_t)d * D_HID + f], h1[(size_t)s * D_HID + f] * norm);
}
__global__ void fb_relu_gemm2(const float* __restrict__ a1, const float* __restrict__ W2,
                              float* __restrict__ h2, int n) {
    int node = blockIdx.x * blockDim.x + threadIdx.x;
    if (node >= n) return;
    float c0 = 0.f, c1 = 0.f;
    const float* row = a1 + (size_t)node * D_HID;
#pragma unroll
    for (int f = 0; f < D_HID; ++f) {
        float r = fmaxf(row[f], 0.f);
        c0 += r * W2[f * N_CLS + 0];
        c1 += r * W2[f * N_CLS + 1];
    }
    h2[(size_t)node * 2 + 0] = c0;
    h2[(size_t)node * 2 + 1] = c1;
}
__global__ void fb_a2_init(const float* __restrict__ h2, const float* __restrict__ dinv,
                           const float* __restrict__ b2, float* __restrict__ a2, int n) {
    int tid = blockIdx.x * blockDim.x + threadIdx.x;
    if (tid >= n * N_CLS) return;
    int node = tid >> 1, c = tid & 1;
    float di = dinv[node];
    a2[tid] = b2[c] + di * di * h2[tid];
}
template<bool I64>
__global__ void fb_agg2(const void* __restrict__ ei, const float* __restrict__ dinv,
                        const float* __restrict__ h2, float* __restrict__ a2,
                        int E, const int* __restrict__ flags) {
    if (flags[FE] != (int)I64) return;
    int e = blockIdx.x * blockDim.x + threadIdx.x;
    if (e >= E) return;
    int s = lde<I64>(ei, (size_t)e);
    int d = lde<I64>(ei, (size_t)E + e);
    float norm = dinv[s] * dinv[d];
    atomicAdd(&a2[(size_t)d * 2 + 0], h2[(size_t)s * 2 + 0] * norm);
    atomicAdd(&a2[(size_t)d * 2 + 1], h2[(size_t)s * 2 + 1] * norm);
}
__global__ void fb_gemm1(const float* __restrict__ x, const float* __restrict__ W1,
                         float* __restrict__ h1, int n) {
    __shared__ float w[D_IN * D_HID];
    for (int i = threadIdx.x; i < D_IN * D_HID; i += blockDim.x) w[i] = W1[i];
    __syncthreads();
    int tid = blockIdx.x * blockDim.x + threadIdx.x;
    int node = tid >> 4, f = tid & 15;
    if (node >= n) return;
    const float4* xr = (const float4*)(x + (size_t)node * D_IN);
    float acc = 0.f;
#pragma unroll
    for (int k4 = 0; k4 < D_IN / 4; ++k4) {
        float4 v = xr[k4];
        int k = k4 * 4;
        acc += v.x * w[(k + 0) * D_HID + f];
        acc += v.y * w[(k + 1) * D_HID + f];
        acc += v.z * w[(k + 2) * D_HID + f];
        acc += v.w * w[(k + 3) * D_HID + f];
    }
    h1[tid] = acc;
}
__global__ void fb_lsm(const float* __restrict__ a2, float* __restrict__ out, int n) {
    int node = blockIdx.x * blockDim.x + threadIdx.x;
    if (node >= n) return;
    float v0 = a2[(size_t)node * 2 + 0];
    float v1 = a2[(size_t)node * 2 + 1];
    float m = fmaxf(v0, v1);
    float lse = m + logf(expf(v0 - m) + expf(v1 - m));
    out[(size_t)node * 2 + 0] = v0 - lse;
    out[(size_t)node * 2 + 1] = v1 - lse;
}

extern "C" void kernel_launch(void* const* d_in, const int* in_sizes, int n_in,
                              void* d_out, int out_size, void* d_ws, size_t ws_size,
                              hipStream_t stream) {
    const float* x  = (const float*)d_in[0];
    const void*  ei = d_in[1];
    const float* W1 = (const float*)d_in[2];
    const float* b1 = (const float*)d_in[3];
    const float* W2 = (const float*)d_in[4];
    const float* b2 = (const float*)d_in[5];

    const int N = in_sizes[0] / D_IN;      // 100000
    const int E = in_sizes[1] / 2;         // 3200000
    const int nb = (N + NPB - 1) / NPB;    // 391

    const int B = 256;
    dim3 blk(B);
    const int nBlkN = (N + B - 1) / B;
    const int nBlkE = (E + B - 1) / B;
    char* ws = (char*)d_ws;

    // ---- workspace layout ----
    const size_t oDinv  = 0;                                   // N f32
    const size_t oGBcnt = (size_t)N * 4;                       // nb u32
    const size_t oBB    = oGBcnt + (size_t)nb * 4;             // (nb+1) int
    const size_t oGcur  = oBB + (size_t)(nb + 1) * 4;          // nb u32
    const size_t oFlag  = oGcur + (size_t)nb * 4;              // 2 int
    const size_t oStage = (oFlag + 8 + 63) & ~(size_t)63;      // E u32
    const size_t oG1h   = oStage + (size_t)E * 4;              // N*16 half
    const size_t oG2    = oG1h + (size_t)N * D_HID * 2;        // N*2 f32
    const size_t needNew = oG2 + (size_t)N * 2 * 4;            // ~17.2 MB

    if (ws_size >= needNew && nb <= MAXB) {
        float*        dinv   = (float*)(ws + oDinv);
        unsigned int* gbcnt  = (unsigned int*)(ws + oGBcnt);
        int*          bbase  = (int*)(ws + oBB);
        unsigned int* gcur   = (unsigned int*)(ws + oGcur);
        int*          flags  = (int*)(ws + oFlag);
        unsigned int* staged = (unsigned int*)(ws + oStage);
        __half*       g1h    = (__half*)(ws + oG1h);
        float2*       g2     = (float2*)(ws + oG2);

        k_detect<<<dim3(1), blk, 0, stream>>>((const int*)ei, flags);
        hipMemsetAsync(gbcnt, 0, (size_t)nb * 4, stream);

        k_bhist<false><<<dim3(256), blk, 0, stream>>>(ei, gbcnt, E, flags);
        k_bhist<true ><<<dim3(256), blk, 0, stream>>>(ei, gbcnt, E, flags);
        k_bscan<<<dim3(1), dim3(MAXB), 0, stream>>>(gbcnt, bbase, gcur, nb);

        dim3 gPart((E + TILE - 1) / TILE);
        k_part<false><<<gPart, dim3(512), 0, stream>>>(ei, gcur, staged, E, flags);
        k_part<true ><<<gPart, dim3(512), 0, stream>>>(ei, gcur, staged, E, flags);

        k_dinv2<<<dim3(nb), dim3(512), 0, stream>>>(staged, bbase, dinv, N);

        dim3 g_nh((N * D_HID + B - 1) / B);
        k_gemm1h<<<g_nh, blk, 0, stream>>>(x, W1, dinv, g1h, N);
        k_agg1b<<<dim3(nb), dim3(1024), 0, stream>>>(staged, bbase, g1h, dinv, b1, W2, g2, N);
        k_agg2b<<<dim3(nb), dim3(512), 0, stream>>>(staged, bbase, g2, dinv, b2,
                                                    (float2*)d_out, N);
    } else {
        // fallback: round-3 atomic path (needs ~14.8 MB)
        float* dinv  = (float*)(ws + 0);
        float* h1    = (float*)(ws + 400128);
        float* a1    = (float*)(ws + 6800256);
        float* h2    = (float*)(ws + 13200384);
        float* a2    = (float*)(ws + 14000512);
        int*   flags = (int*)  (ws + 14800640);

        k_detect<<<dim3(1), blk, 0, stream>>>((const int*)ei, flags);
        fb_deg_init<<<dim3(nBlkN), blk, 0, stream>>>((unsigned int*)dinv, N);
        fb_deg_count<false><<<dim3(nBlkE), blk, 0, stream>>>(ei, (unsigned int*)dinv, E, flags);
        fb_deg_count<true ><<<dim3(nBlkE), blk, 0, stream>>>(ei, (unsigned int*)dinv, E, flags);
        fb_dinv_inplace<<<dim3(nBlkN), blk, 0, stream>>>(dinv, N);

        dim3 g_nh((N * D_HID + B - 1) / B);
        fb_gemm1<<<g_nh, blk, 0, stream>>>(x, W1, h1, N);
        fb_a1_init<<<g_nh, blk, 0, stream>>>(h1, dinv, b1, a1, N);
        dim3 g_eh(((size_t)E * D_HID + B - 1) / B);
        fb_agg1<false><<<g_eh, blk, 0, stream>>>(ei, dinv, h1, a1, E, flags);
        fb_agg1<true ><<<g_eh, blk, 0, stream>>>(ei, dinv, h1, a1, E, flags);
        fb_relu_gemm2<<<dim3(nBlkN), blk, 0, stream>>>(a1, W2, h2, N);
        dim3 g_n2((N * N_CLS + B - 1) / B);
        fb_a2_init<<<g_n2, blk, 0, stream>>>(h2, dinv, b2, a2, N);
        fb_agg2<false><<<dim3(nBlkE), blk, 0, stream>>>(ei, dinv, h2, a2, E, flags);
        fb_agg2<true ><<<dim3(nBlkE), blk, 0, stream>>>(ei, dinv, h2, a2, E, flags);
        fb_lsm<<<dim3(nBlkN), blk, 0, stream>>>(a2, (float*)d_out, N);
    }
}

// Round 8
// 275.032 us; speedup vs baseline: 2.0791x; 2.0791x over previous
//
#include <hip/hip_runtime.h>
#include <hip/hip_bf16.h>
#include <hip/hip_fp16.h>

#define D_IN  128
#define D_HID 16
#define N_CLS 2
#define NPB   256          // nodes per bucket (bucket = dst >> 8)
#define MAXB  512          // LDS-side max buckets (supports N <= 131072)
#define TILE  8192         // edges per k_part workgroup
#define CAP   9216         // per-bucket LDS staging capacity (mean 8192)
#define OVF_CAP 780000     // overflow scratch capacity (uints, in g1h region)

#define FE 0   // edge_index storage: 0 = int32, 1 = int64

// ---------------- edge dtype detection (1 block) ----------------
__global__ void k_detect(const int* __restrict__ ev, int* __restrict__ flags) {
    __shared__ int sE;
    if (threadIdx.x == 0) sE = 0;
    __syncthreads();
    if (ev[2 * threadIdx.x + 1] != 0) atomicOr(&sE, 1);
    __syncthreads();
    if (threadIdx.x == 0) flags[FE] = sE ? 0 : 1;
}

template<bool I64>
__device__ __forceinline__ int lde(const void* p, size_t i) {
    if constexpr (I64) return (int)((const long long*)p)[i];
    else               return ((const int*)p)[i];
}

// ---------------- bucket histogram (LDS-privatized, grid-stride) ----------------
template<bool I64>
__global__ void k_bhist(const void* __restrict__ ei, unsigned int* __restrict__ gbcnt,
                        int E, const int* __restrict__ flags) {
    if (flags[FE] != (int)I64) return;
    __shared__ unsigned int h[MAXB];
    for (int i = threadIdx.x; i < MAXB; i += blockDim.x) h[i] = 0u;
    __syncthreads();
    int stride = gridDim.x * blockDim.x;
    for (int e = blockIdx.x * blockDim.x + threadIdx.x; e < E; e += stride) {
        int d = lde<I64>(ei, (size_t)E + e);
        atomicAdd(&h[d >> 8], 1u);
    }
    __syncthreads();
    for (int i = threadIdx.x; i < MAXB; i += blockDim.x)
        if (h[i]) atomicAdd(&gbcnt[i], h[i]);
}

// ---------------- bucket scan: bbase (exclusive) + cursor init ----------------
__global__ void k_bscan(const unsigned int* __restrict__ gbcnt, int* __restrict__ bbase,
                        unsigned int* __restrict__ gcur, int nb) {
    __shared__ int s[MAXB];
    int tid = threadIdx.x;
    int v = (tid < nb) ? (int)gbcnt[tid] : 0;
    s[tid] = v;
    __syncthreads();
#pragma unroll
    for (int off = 1; off < MAXB; off <<= 1) {
        int t = (tid >= off) ? s[tid - off] : 0;
        __syncthreads();
        s[tid] += t;
        __syncthreads();
    }
    int excl = s[tid] - v;
    if (tid <= nb) bbase[tid] = (tid < nb) ? excl : s[nb - 1];  // bbase[nb] = total
    if (tid < nb)  gcur[tid] = (unsigned int)excl;
}

// ---------------- pass 1: LDS-staged partition by bucket ----------------
template<bool I64>
__global__ __launch_bounds__(512) void k_part(
        const void* __restrict__ ei, unsigned int* __restrict__ gcur,
        unsigned int* __restrict__ staged, int E, const int* __restrict__ flags) {
    if (flags[FE] != (int)I64) return;
    __shared__ unsigned int sbuf[TILE];       // 32 KB packed values
    __shared__ unsigned short bbuf[TILE];     // 16 KB bucket ids
    __shared__ int hist[MAXB], scn[MAXB], lbase[MAXB], gb[MAXB];  // 8 KB
    int tid = threadIdx.x;
    int t0 = blockIdx.x * TILE;

    hist[tid] = 0;
    __syncthreads();

    int myB[16]; unsigned int myP[16]; int myR[16];
#pragma unroll
    for (int k = 0; k < 16; ++k) {
        int e = t0 + k * 512 + tid;
        if (e < E) {
            int s = lde<I64>(ei, (size_t)e);
            int d = lde<I64>(ei, (size_t)E + e);
            int b = d >> 8;
            myB[k] = b;
            myP[k] = ((unsigned int)s << 8) | (unsigned int)(d & 255);
            myR[k] = atomicAdd(&hist[b], 1);
        } else myB[k] = -1;
    }
    __syncthreads();

    int v = hist[tid];
    scn[tid] = v;
    __syncthreads();
#pragma unroll
    for (int off = 1; off < MAXB; off <<= 1) {
        int t = (tid >= off) ? scn[tid - off] : 0;
        __syncthreads();
        scn[tid] += t;
        __syncthreads();
    }
    int excl = scn[tid] - v;
    lbase[tid] = excl;
    int gb_ = 0;
    if (v > 0) gb_ = (int)atomicAdd(&gcur[tid], (unsigned int)v);
    gb[tid] = gb_;
    __syncthreads();

#pragma unroll
    for (int k = 0; k < 16; ++k) {
        if (myB[k] >= 0) {
            int pos = lbase[myB[k]] + myR[k];
            sbuf[pos] = myP[k];
            bbuf[pos] = (unsigned short)myB[k];
        }
    }
    __syncthreads();

    int tot = scn[MAXB - 1];
    for (int i = tid; i < tot; i += 512) {
        int b = bbuf[i];
        staged[(size_t)gb[b] + (i - lbase[b])] = sbuf[i];  // ~84B contiguous runs
    }
}

// ---------------- pass 2: per-bucket CSR fill (in-place) + dinv + row_ptr ----------------
__global__ __launch_bounds__(512) void k_fill2(
        unsigned int* __restrict__ staged,      // aliases csr output
        const int* __restrict__ bbase,
        float* __restrict__ dinv, int* __restrict__ row_ptr,
        unsigned int* __restrict__ ovf, unsigned int* __restrict__ ovfbuf,
        int N, int E, int nb) {
    __shared__ int h[NPB], scn2[NPB], cur[NPB];
    __shared__ int outb[CAP];                   // 36 KB
    __shared__ long long sOff;
    int tid = threadIdx.x;
    int b = blockIdx.x;
    int s0 = bbase[b], s1 = bbase[b + 1];
    int cnt = s1 - s0;
    int base_node = b * NPB;
    int nn = N - base_node; if (nn > NPB) nn = NPB;

    if (tid < NPB) h[tid] = 0;
    __syncthreads();
    for (int i = tid; i < cnt; i += 512)
        atomicAdd(&h[staged[(size_t)s0 + i] & 255], 1);
    __syncthreads();
    int hv = (tid < NPB) ? h[tid] : 0;
    if (tid < NPB) scn2[tid] = hv;
    __syncthreads();
#pragma unroll
    for (int off = 1; off < NPB; off <<= 1) {
        int t = (tid >= off && tid < NPB) ? scn2[tid - off] : 0;
        __syncthreads();
        if (tid < NPB) scn2[tid] += t;
        __syncthreads();
    }
    if (tid < NPB) cur[tid] = scn2[tid] - hv;
    if (tid < nn) {
        dinv[base_node + tid] = rsqrtf((float)(hv + 1));       // +1 self loop
        row_ptr[base_node + tid] = s0 + (scn2[tid] - hv);
    }
    if (b == nb - 1 && tid == 0) row_ptr[N] = E;
    __syncthreads();

    if (cnt <= CAP) {
        for (int i = tid; i < cnt; i += 512) {
            unsigned int p = staged[(size_t)s0 + i];
            int pos = atomicAdd(&cur[p & 255], 1);
            outb[pos] = (int)(p >> 8);
        }
        __syncthreads();
        for (int i = tid; i < cnt; i += 512)
            ((int*)staged)[(size_t)s0 + i] = outb[i];
    } else {
        if (tid == 0) {
            unsigned int o = atomicAdd(ovf, (unsigned int)cnt);
            sOff = ((size_t)o + (size_t)cnt <= (size_t)OVF_CAP) ? (long long)o : -1;
        }
        __syncthreads();
        if (sOff >= 0) {
            unsigned int* scr = ovfbuf + sOff;
            for (int i = tid; i < cnt; i += 512) scr[i] = staged[(size_t)s0 + i];
            __syncthreads();
            for (int i = tid; i < cnt; i += 512) {
                unsigned int p = scr[i];
                int pos = atomicAdd(&cur[p & 255], 1);
                ((int*)staged)[(size_t)s0 + pos] = (int)(p >> 8);
            }
        }
    }
}

// ---------------- layer 1 GEMM: g1h = (half)(dinv * (x @ W1)) ----------------
__global__ void k_gemm1h(const float* __restrict__ x, const float* __restrict__ W1,
                         const float* __restrict__ dinv, __half* __restrict__ g1h, int n) {
    __shared__ float w[D_IN * D_HID];  // 8 KiB
    for (int i = threadIdx.x; i < D_IN * D_HID; i += blockDim.x)
        w[i] = W1[i];
    __syncthreads();
    int tid = blockIdx.x * blockDim.x + threadIdx.x;
    int node = tid >> 4, f = tid & 15;
    if (node >= n) return;
    const float4* xr = (const float4*)(x + (size_t)node * D_IN);
    float acc = 0.f;
#pragma unroll
    for (int k4 = 0; k4 < D_IN / 4; ++k4) {
        float4 v = xr[k4];
        int k = k4 * 4;
        acc += v.x * w[(k + 0) * D_HID + f];
        acc += v.y * w[(k + 1) * D_HID + f];
        acc += v.z * w[(k + 2) * D_HID + f];
        acc += v.w * w[(k + 3) * D_HID + f];
    }
    g1h[tid] = __float2half(dinv[node] * acc);
}

// ---------------- fused: gather-agg1 + bias + ReLU + GEMM2 -> g2 ----------------
// Register accumulation, NO atomics. 16 lanes per node.
__global__ void k_agg1f(const int* __restrict__ csr_src, const int* __restrict__ row_ptr,
                        const float* __restrict__ dinv, const __half* __restrict__ g1h,
                        const float* __restrict__ b1, const float* __restrict__ W2,
                        float2* __restrict__ g2, int n) {
    int tid = blockIdx.x * blockDim.x + threadIdx.x;
    int node = tid >> 4, f = tid & 15;
    if (node >= n) return;
    int beg = row_ptr[node], end = row_ptr[node + 1];
    float acc = __half2float(g1h[(size_t)node * D_HID + f]);   // self-loop term
    int gbase = (threadIdx.x & 63) & 48;
    for (int j = beg; j < end; j += 16) {
        int m = end - j; if (m > 16) m = 16;
        int myS = (j + f < end) ? csr_src[j + f] : 0;
        for (int k = 0; k < m; ++k) {
            int s = __shfl(myS, gbase + k, 64);
            acc += __half2float(g1h[(size_t)s * D_HID + f]);
        }
    }
    float di = dinv[node];
    float r = fmaxf(b1[f] + di * acc, 0.f);
    float c0 = r * W2[f * N_CLS + 0];
    float c1 = r * W2[f * N_CLS + 1];
#pragma unroll
    for (int m = 8; m >= 1; m >>= 1) {
        c0 += __shfl_xor(c0, m, 64);
        c1 += __shfl_xor(c1, m, 64);
    }
    if (f == 0) g2[node] = make_float2(di * c0, di * c1);
}

// ---------------- fused: gather-agg2 + bias + log_softmax -> out ----------------
__global__ void k_agg2lsm(const int* __restrict__ csr_src, const int* __restrict__ row_ptr,
                          const float* __restrict__ dinv, const float2* __restrict__ g2,
                          const float* __restrict__ b2, float2* __restrict__ out, int n) {
    int node = blockIdx.x * blockDim.x + threadIdx.x;
    if (node >= n) return;
    float2 self = g2[node];
    float a0 = self.x, a1 = self.y;
    int beg = row_ptr[node], end = row_ptr[node + 1];
    for (int j = beg; j < end; ++j) {
        float2 t = g2[csr_src[j]];
        a0 += t.x; a1 += t.y;
    }
    float di = dinv[node];
    float v0 = b2[0] + di * a0;
    float v1 = b2[1] + di * a1;
    float mx = fmaxf(v0, v1);
    float lse = mx + logf(expf(v0 - mx) + expf(v1 - mx));
    out[node] = make_float2(v0 - lse, v1 - lse);
}

// =================== fallback (round-3 atomic path, if ws too small) ===================
__global__ void fb_deg_init(unsigned int* __restrict__ deg, int n) {
    int i = blockIdx.x * blockDim.x + threadIdx.x;
    if (i < n) deg[i] = 1u;
}
template<bool I64>
__global__ void fb_deg_count(const void* __restrict__ ei, unsigned int* __restrict__ deg,
                             int E, const int* __restrict__ flags) {
    if (flags[FE] != (int)I64) return;
    int e = blockIdx.x * blockDim.x + threadIdx.x;
    if (e < E) atomicAdd(&deg[lde<I64>(ei, (size_t)E + e)], 1u);
}
__global__ void fb_dinv_inplace(float* __restrict__ dinv, int n) {
    int i = blockIdx.x * blockDim.x + threadIdx.x;
    if (i < n) {
        unsigned int u = ((const unsigned int*)dinv)[i];
        dinv[i] = rsqrtf((float)u);
    }
}
__global__ void fb_a1_init(const float* __restrict__ h1, const float* __restrict__ dinv,
                           const float* __restrict__ b1, float* __restrict__ a1, int n) {
    int tid = blockIdx.x * blockDim.x + threadIdx.x;
    if (tid >= n * D_HID) return;
    int node = tid >> 4, f = tid & 15;
    float di = dinv[node];
    a1[tid] = b1[f] + di * di * h1[tid];
}
template<bool I64>
__global__ void fb_agg1(const void* __restrict__ ei, const float* __restrict__ dinv,
                        const float* __restrict__ h1, float* __restrict__ a1,
                        int E, const int* __restrict__ flags) {
    if (flags[FE] != (int)I64) return;
    int tid = blockIdx.x * blockDim.x + threadIdx.x;
    int e = tid >> 4, f = tid & 15;
    if (e >= E) return;
    int s = lde<I64>(ei, (size_t)e);
    int d = lde<I64>(ei, (size_t)E + e);
    float norm = dinv[s] * dinv[d];
    atomicAdd(&a1[(size_t)d * D_HID + f], h1[(size_t)s * D_HID + f] * norm);
}
__global__ void fb_relu_gemm2(const float* __restrict__ a1, const float* __restrict__ W2,
                              float* __restrict__ h2, int n) {
    int node = blockIdx.x * blockDim.x + threadIdx.x;
    if (node >= n) return;
    float c0 = 0.f, c1 = 0.f;
    const float* row = a1 + (size_t)node * D_HID;
#pragma unroll
    for (int f = 0; f < D_HID; ++f) {
        float r = fmaxf(row[f], 0.f);
        c0 += r * W2[f * N_CLS + 0];
        c1 += r * W2[f * N_CLS + 1];
    }
    h2[(size_t)node * 2 + 0] = c0;
    h2[(size_t)node * 2 + 1] = c1;
}
__global__ void fb_a2_init(const float* __restrict__ h2, const float* __restrict__ dinv,
                           const float* __restrict__ b2, float* __restrict__ a2, int n) {
    int tid = blockIdx.x * blockDim.x + threadIdx.x;
    if (tid >= n * N_CLS) return;
    int node = tid >> 1, c = tid & 1;
    float di = dinv[node];
    a2[tid] = b2[c] + di * di * h2[tid];
}
template<bool I64>
__global__ void fb_agg2(const void* __restrict__ ei, const float* __restrict__ dinv,
                        const float* __restrict__ h2, float* __restrict__ a2,
                        int E, const int* __restrict__ flags) {
    if (flags[FE] != (int)I64) return;
    int e = blockIdx.x * blockDim.x + threadIdx.x;
    if (e >= E) return;
    int s = lde<I64>(ei, (size_t)e);
    int d = lde<I64>(ei, (size_t)E + e);
    float norm = dinv[s] * dinv[d];
    atomicAdd(&a2[(size_t)d * 2 + 0], h2[(size_t)s * 2 + 0] * norm);
    atomicAdd(&a2[(size_t)d * 2 + 1], h2[(size_t)s * 2 + 1] * norm);
}
__global__ void fb_gemm1(const float* __restrict__ x, const float* __restrict__ W1,
                         float* __restrict__ h1, int n) {
    __shared__ float w[D_IN * D_HID];
    for (int i = threadIdx.x; i < D_IN * D_HID; i += blockDim.x) w[i] = W1[i];
    __syncthreads();
    int tid = blockIdx.x * blockDim.x + threadIdx.x;
    int node = tid >> 4, f = tid & 15;
    if (node >= n) return;
    const float4* xr = (const float4*)(x + (size_t)node * D_IN);
    float acc = 0.f;
#pragma unroll
    for (int k4 = 0; k4 < D_IN / 4; ++k4) {
        float4 v = xr[k4];
        int k = k4 * 4;
        acc += v.x * w[(k + 0) * D_HID + f];
        acc += v.y * w[(k + 1) * D_HID + f];
        acc += v.z * w[(k + 2) * D_HID + f];
        acc += v.w * w[(k + 3) * D_HID + f];
    }
    h1[tid] = acc;
}
__global__ void fb_lsm(const float* __restrict__ a2, float* __restrict__ out, int n) {
    int node = blockIdx.x * blockDim.x + threadIdx.x;
    if (node >= n) return;
    float v0 = a2[(size_t)node * 2 + 0];
    float v1 = a2[(size_t)node * 2 + 1];
    float m = fmaxf(v0, v1);
    float lse = m + logf(expf(v0 - m) + expf(v1 - m));
    out[(size_t)node * 2 + 0] = v0 - lse;
    out[(size_t)node * 2 + 1] = v1 - lse;
}

extern "C" void kernel_launch(void* const* d_in, const int* in_sizes, int n_in,
                              void* d_out, int out_size, void* d_ws, size_t ws_size,
                              hipStream_t stream) {
    const float* x  = (const float*)d_in[0];
    const void*  ei = d_in[1];
    const float* W1 = (const float*)d_in[2];
    const float* b1 = (const float*)d_in[3];
    const float* W2 = (const float*)d_in[4];
    const float* b2 = (const float*)d_in[5];

    const int N = in_sizes[0] / D_IN;      // 100000
    const int E = in_sizes[1] / 2;         // 3200000
    const int nb = (N + NPB - 1) / NPB;    // 391

    const int B = 256;
    dim3 blk(B);
    const int nBlkN = (N + B - 1) / B;
    const int nBlkE = (E + B - 1) / B;
    char* ws = (char*)d_ws;

    // ---- workspace layout (bytes) ----
    const size_t oDinv  = 0;                                   // N f32
    const size_t oRow   = (size_t)N * 4;                       // (N+1) int
    const size_t oGBcnt = oRow + (size_t)(N + 1) * 4;          // nb u32
    const size_t oOvf   = oGBcnt + (size_t)nb * 4;             // 1 u32
    const size_t oBB    = oOvf + 4;                            // (nb+1) int
    const size_t oGcur  = oBB + (size_t)(nb + 1) * 4;          // nb u32
    const size_t oFlag  = oGcur + (size_t)nb * 4;              // 2 int
    const size_t oStage = (oFlag + 8 + 63) & ~(size_t)63;      // E u32 (later: csr_src)
    const size_t oG1h   = oStage + (size_t)E * 4;              // N*16 half (also ovf scratch)
    const size_t oG2    = oG1h + (size_t)N * D_HID * 2;        // N*2 f32
    const size_t needNew = oG2 + (size_t)N * 2 * 4;            // ~17.7 MB

    if (ws_size >= needNew && nb <= MAXB) {
        float*        dinv    = (float*)(ws + oDinv);
        int*          row_ptr = (int*)(ws + oRow);
        unsigned int* gbcnt   = (unsigned int*)(ws + oGBcnt);
        unsigned int* ovf     = (unsigned int*)(ws + oOvf);
        int*          bbase   = (int*)(ws + oBB);
        unsigned int* gcur    = (unsigned int*)(ws + oGcur);
        int*          flags   = (int*)(ws + oFlag);
        unsigned int* staged  = (unsigned int*)(ws + oStage);  // becomes csr_src in-place
        __half*       g1h     = (__half*)(ws + oG1h);
        float2*       g2      = (float2*)(ws + oG2);
        int*          csr_src = (int*)staged;

        k_detect<<<dim3(1), blk, 0, stream>>>((const int*)ei, flags);
        hipMemsetAsync(gbcnt, 0, (size_t)nb * 4 + 4, stream);  // gbcnt + ovf

        k_bhist<false><<<dim3(256), blk, 0, stream>>>(ei, gbcnt, E, flags);
        k_bhist<true ><<<dim3(256), blk, 0, stream>>>(ei, gbcnt, E, flags);
        k_bscan<<<dim3(1), dim3(MAXB), 0, stream>>>(gbcnt, bbase, gcur, nb);

        dim3 gPart((E + TILE - 1) / TILE);
        k_part<false><<<gPart, dim3(512), 0, stream>>>(ei, gcur, staged, E, flags);
        k_part<true ><<<gPart, dim3(512), 0, stream>>>(ei, gcur, staged, E, flags);

        k_fill2<<<dim3(nb), dim3(512), 0, stream>>>(staged, bbase, dinv, row_ptr,
                                                    ovf, (unsigned int*)g1h, N, E, nb);

        dim3 g_nh((N * D_HID + B - 1) / B);
        k_gemm1h<<<g_nh, blk, 0, stream>>>(x, W1, dinv, g1h, N);
        k_agg1f<<<g_nh, blk, 0, stream>>>(csr_src, row_ptr, dinv, g1h, b1, W2, g2, N);
        k_agg2lsm<<<dim3(nBlkN), blk, 0, stream>>>(csr_src, row_ptr, dinv, g2, b2,
                                                   (float2*)d_out, N);
    } else {
        // fallback: round-3 atomic path (needs ~14.8 MB)
        float* dinv  = (float*)(ws + 0);
        float* h1    = (float*)(ws + 400128);
        float* a1    = (float*)(ws + 6800256);
        float* h2    = (float*)(ws + 13200384);
        float* a2    = (float*)(ws + 14000512);
        int*   flags = (int*)  (ws + 14800640);

        k_detect<<<dim3(1), blk, 0, stream>>>((const int*)ei, flags);
        fb_deg_init<<<dim3(nBlkN), blk, 0, stream>>>((unsigned int*)dinv, N);
        fb_deg_count<false><<<dim3(nBlkE), blk, 0, stream>>>(ei, (unsigned int*)dinv, E, flags);
        fb_deg_count<true ><<<dim3(nBlkE), blk, 0, stream>>>(ei, (unsigned int*)dinv, E, flags);
        fb_dinv_inplace<<<dim3(nBlkN), blk, 0, stream>>>(dinv, N);

        dim3 g_nh((N * D_HID + B - 1) / B);
        fb_gemm1<<<g_nh, blk, 0, stream>>>(x, W1, h1, N);
        fb_a1_init<<<g_nh, blk, 0, stream>>>(h1, dinv, b1, a1, N);
        dim3 g_eh(((size_t)E * D_HID + B - 1) / B);
        fb_agg1<false><<<g_eh, blk, 0, stream>>>(ei, dinv, h1, a1, E, flags);
        fb_agg1<true ><<<g_eh, blk, 0, stream>>>(ei, dinv, h1, a1, E, flags);
        fb_relu_gemm2<<<dim3(nBlkN), blk, 0, stream>>>(a1, W2, h2, N);
        dim3 g_n2((N * N_CLS + B - 1) / B);
        fb_a2_init<<<g_n2, blk, 0, stream>>>(h2, dinv, b2, a2, N);
        fb_agg2<false><<<dim3(nBlkE), blk, 0, stream>>>(ei, dinv, h2, a2, E, flags);
        fb_agg2<true ><<<dim3(nBlkE), blk, 0, stream>>>(ei, dinv, h2, a2, E, flags);
        fb_lsm<<<dim3(nBlkN), blk, 0, stream>>>(a2, (float*)d_out, N);
    }
}

// Round 9
// 270.472 us; speedup vs baseline: 2.1142x; 1.0169x over previous
//
#include <hip/hip_runtime.h>
#include <hip/hip_bf16.h>
#include <hip/hip_fp16.h>

#define D_IN  128
#define D_HID 16
#define N_CLS 2
#define NPB   256          // nodes per bucket (bucket = dst >> 8)
#define MAXB  512          // max buckets (N <= 131072)
#define TILE  8192         // edges per k_part workgroup
#define FPSCALE 65536.0f   // Q15.16 fixed-point scale for LDS int accumulation
#define FPINV   (1.0f / 65536.0f)

#define FE 0   // edge_index storage: 0 = int32, 1 = int64

// ---------------- edge dtype detection (1 block) ----------------
__global__ void k_detect(const int* __restrict__ ev, int* __restrict__ flags) {
    __shared__ int sE;
    if (threadIdx.x == 0) sE = 0;
    __syncthreads();
    if (ev[2 * threadIdx.x + 1] != 0) atomicOr(&sE, 1);
    __syncthreads();
    if (threadIdx.x == 0) flags[FE] = sE ? 0 : 1;
}

template<bool I64>
__device__ __forceinline__ int lde(const void* p, size_t i) {
    if constexpr (I64) return (int)((const long long*)p)[i];
    else               return ((const int*)p)[i];
}

// ---------------- bucket histogram (LDS-privatized, grid-stride) ----------------
template<bool I64>
__global__ void k_bhist(const void* __restrict__ ei, unsigned int* __restrict__ gbcnt,
                        int E, const int* __restrict__ flags) {
    if (flags[FE] != (int)I64) return;
    __shared__ unsigned int h[MAXB];
    for (int i = threadIdx.x; i < MAXB; i += blockDim.x) h[i] = 0u;
    __syncthreads();
    int stride = gridDim.x * blockDim.x;
    for (int e = blockIdx.x * blockDim.x + threadIdx.x; e < E; e += stride) {
        int d = lde<I64>(ei, (size_t)E + e);
        atomicAdd(&h[d >> 8], 1u);
    }
    __syncthreads();
    for (int i = threadIdx.x; i < MAXB; i += blockDim.x)
        if (h[i]) atomicAdd(&gbcnt[i], h[i]);
}

// ---------------- bucket scan: bbase (exclusive) + cursor init ----------------
__global__ void k_bscan(const unsigned int* __restrict__ gbcnt, int* __restrict__ bbase,
                        unsigned int* __restrict__ gcur, int nb) {
    __shared__ int s[MAXB];
    int tid = threadIdx.x;
    int v = (tid < nb) ? (int)gbcnt[tid] : 0;
    s[tid] = v;
    __syncthreads();
#pragma unroll
    for (int off = 1; off < MAXB; off <<= 1) {
        int t = (tid >= off) ? s[tid - off] : 0;
        __syncthreads();
        s[tid] += t;
        __syncthreads();
    }
    int excl = s[tid] - v;
    if (tid <= nb) bbase[tid] = (tid < nb) ? excl : s[nb - 1];  // bbase[nb] = total
    if (tid < nb)  gcur[tid] = (unsigned int)excl;
}

// ---------------- pass 1: LDS-staged partition by bucket ----------------
template<bool I64>
__global__ __launch_bounds__(512) void k_part(
        const void* __restrict__ ei, unsigned int* __restrict__ gcur,
        unsigned int* __restrict__ staged, int E, const int* __restrict__ flags) {
    if (flags[FE] != (int)I64) return;
    __shared__ unsigned int sbuf[TILE];       // 32 KB packed values
    __shared__ unsigned short bbuf[TILE];     // 16 KB bucket ids
    __shared__ int hist[MAXB], scn[MAXB], lbase[MAXB], gb[MAXB];  // 8 KB
    int tid = threadIdx.x;
    int t0 = blockIdx.x * TILE;

    hist[tid] = 0;
    __syncthreads();

    int myB[16]; unsigned int myP[16]; int myR[16];
#pragma unroll
    for (int k = 0; k < 16; ++k) {
        int e = t0 + k * 512 + tid;
        if (e < E) {
            int s = lde<I64>(ei, (size_t)e);
            int d = lde<I64>(ei, (size_t)E + e);
            int b = d >> 8;
            myB[k] = b;
            myP[k] = ((unsigned int)s << 8) | (unsigned int)(d & 255);
            myR[k] = atomicAdd(&hist[b], 1);
        } else myB[k] = -1;
    }
    __syncthreads();

    int v = hist[tid];
    scn[tid] = v;
    __syncthreads();
#pragma unroll
    for (int off = 1; off < MAXB; off <<= 1) {
        int t = (tid >= off) ? scn[tid - off] : 0;
        __syncthreads();
        scn[tid] += t;
        __syncthreads();
    }
    int excl = scn[tid] - v;
    lbase[tid] = excl;
    int gb_ = 0;
    if (v > 0) gb_ = (int)atomicAdd(&gcur[tid], (unsigned int)v);
    gb[tid] = gb_;
    __syncthreads();

#pragma unroll
    for (int k = 0; k < 16; ++k) {
        if (myB[k] >= 0) {
            int pos = lbase[myB[k]] + myR[k];
            sbuf[pos] = myP[k];
            bbuf[pos] = (unsigned short)myB[k];
        }
    }
    __syncthreads();

    int tot = scn[MAXB - 1];
    for (int i = tid; i < tot; i += 512) {
        int b = bbuf[i];
        staged[(size_t)gb[b] + (i - lbase[b])] = sbuf[i];  // ~84B contiguous runs
    }
}

// ---------------- per-bucket degree -> dinv ----------------
__global__ __launch_bounds__(512) void k_dinv2(
        const unsigned int* __restrict__ staged, const int* __restrict__ bbase,
        float* __restrict__ dinv, int N) {
    __shared__ unsigned int h[NPB];
    int tid = threadIdx.x, b = blockIdx.x;
    int s0 = bbase[b], cnt = bbase[b + 1] - s0;
    if (tid < NPB) h[tid] = 0u;
    __syncthreads();
    for (int j = tid; j < cnt; j += 512)
        atomicAdd(&h[staged[(size_t)s0 + j] & 255], 1u);
    __syncthreads();
    int base = b * NPB, nn = N - base; if (nn > NPB) nn = NPB;
    if (tid < nn) dinv[base + tid] = rsqrtf((float)(h[tid] + 1u));  // +1 self loop
}

// ---------------- layer 1 GEMM: g1h = (half)(dinv * (x @ W1)) ----------------
__global__ void k_gemm1h(const float* __restrict__ x, const float* __restrict__ W1,
                         const float* __restrict__ dinv, __half* __restrict__ g1h, int n) {
    __shared__ float w[D_IN * D_HID];  // 8 KiB
    for (int i = threadIdx.x; i < D_IN * D_HID; i += blockDim.x)
        w[i] = W1[i];
    __syncthreads();
    int tid = blockIdx.x * blockDim.x + threadIdx.x;
    int node = tid >> 4, f = tid & 15;
    if (node >= n) return;
    const float4* xr = (const float4*)(x + (size_t)node * D_IN);
    float acc = 0.f;
#pragma unroll
    for (int k4 = 0; k4 < D_IN / 4; ++k4) {
        float4 v = xr[k4];
        int k = k4 * 4;
        acc += v.x * w[(k + 0) * D_HID + f];
        acc += v.y * w[(k + 1) * D_HID + f];
        acc += v.z * w[(k + 2) * D_HID + f];
        acc += v.w * w[(k + 3) * D_HID + f];
    }
    g1h[tid] = __float2half(dinv[node] * acc);
}

// ---------------- bucket-major agg1 (Q15.16 int LDS atomics) + bias+ReLU+GEMM2 -> g2 ----------------
__global__ __launch_bounds__(1024) void k_agg1b(
        const unsigned int* __restrict__ staged, const int* __restrict__ bbase,
        const __half* __restrict__ g1h, const float* __restrict__ dinv,
        const float* __restrict__ b1, const float* __restrict__ W2,
        float2* __restrict__ g2, int N) {
    __shared__ int accI[NPB * D_HID];   // 16 KB
    int tid = threadIdx.x, b = blockIdx.x;
    int s0 = bbase[b], cnt = bbase[b + 1] - s0;
    int base = b * NPB;
    for (int i = tid; i < NPB * D_HID; i += 1024) accI[i] = 0;
    __syncthreads();
    int f = tid & 15;
    for (int j = tid >> 4; j < cnt; j += 64) {
        unsigned int p = staged[(size_t)s0 + j];   // broadcast within 16-lane group
        int s = (int)(p >> 8), dl = (int)(p & 255);
        float v = __half2float(g1h[(size_t)s * D_HID + f]);
        atomicAdd(&accI[dl * D_HID + f], __float2int_rn(v * FPSCALE));  // native ds_add
    }
    __syncthreads();
    int nn = N - base; if (nn > NPB) nn = NPB;
    for (int n = tid >> 4; n < nn; n += 64) {
        int gn = base + n;
        float acc = (float)accI[n * D_HID + f] * FPINV
                  + __half2float(g1h[(size_t)gn * D_HID + f]);   // + self loop
        float di = dinv[gn];
        float r = fmaxf(b1[f] + di * acc, 0.f);
        float c0 = r * W2[f * N_CLS + 0];
        float c1 = r * W2[f * N_CLS + 1];
#pragma unroll
        for (int m = 8; m >= 1; m >>= 1) {
            c0 += __shfl_xor(c0, m, 64);
            c1 += __shfl_xor(c1, m, 64);
        }
        if (f == 0) g2[gn] = make_float2(di * c0, di * c1);
    }
}

// ---------------- bucket-major agg2 (Q15.16 int LDS atomics) + bias + log_softmax -> out ----------------
__global__ __launch_bounds__(512) void k_agg2b(
        const unsigned int* __restrict__ staged, const int* __restrict__ bbase,
        const float2* __restrict__ g2, const float* __restrict__ dinv,
        const float* __restrict__ b2, float2* __restrict__ out, int N) {
    __shared__ int accI[NPB * 2];   // 2 KB
    int tid = threadIdx.x, b = blockIdx.x;
    int s0 = bbase[b], cnt = bbase[b + 1] - s0;
    int base = b * NPB;
    for (int i = tid; i < NPB * 2; i += 512) accI[i] = 0;
    __syncthreads();
    for (int j = tid; j < cnt; j += 512) {
        unsigned int p = staged[(size_t)s0 + j];
        int s = (int)(p >> 8), dl = (int)(p & 255);
        float2 t = g2[s];
        atomicAdd(&accI[dl * 2 + 0], __float2int_rn(t.x * FPSCALE));
        atomicAdd(&accI[dl * 2 + 1], __float2int_rn(t.y * FPSCALE));
    }
    __syncthreads();
    int nn = N - base; if (nn > NPB) nn = NPB;
    for (int n = tid; n < nn; n += 512) {
        int gn = base + n;
        float2 self = g2[gn];
        float di = dinv[gn];
        float v0 = b2[0] + di * ((float)accI[n * 2 + 0] * FPINV + self.x);
        float v1 = b2[1] + di * ((float)accI[n * 2 + 1] * FPINV + self.y);
        float mx = fmaxf(v0, v1);
        float lse = mx + logf(expf(v0 - mx) + expf(v1 - mx));
        out[gn] = make_float2(v0 - lse, v1 - lse);
    }
}

// =================== fallback (round-3 atomic path, if ws too small) ===================
__global__ void fb_deg_init(unsigned int* __restrict__ deg, int n) {
    int i = blockIdx.x * blockDim.x + threadIdx.x;
    if (i < n) deg[i] = 1u;
}
template<bool I64>
__global__ void fb_deg_count(const void* __restrict__ ei, unsigned int* __restrict__ deg,
                             int E, const int* __restrict__ flags) {
    if (flags[FE] != (int)I64) return;
    int e = blockIdx.x * blockDim.x + threadIdx.x;
    if (e < E) atomicAdd(&deg[lde<I64>(ei, (size_t)E + e)], 1u);
}
__global__ void fb_dinv_inplace(float* __restrict__ dinv, int n) {
    int i = blockIdx.x * blockDim.x + threadIdx.x;
    if (i < n) {
        unsigned int u = ((const unsigned int*)dinv)[i];
        dinv[i] = rsqrtf((float)u);
    }
}
__global__ void fb_a1_init(const float* __restrict__ h1, const float* __restrict__ dinv,
                           const float* __restrict__ b1, float* __restrict__ a1, int n) {
    int tid = blockIdx.x * blockDim.x + threadIdx.x;
    if (tid >= n * D_HID) return;
    int node = tid >> 4, f = tid & 15;
    float di = dinv[node];
    a1[tid] = b1[f] + di * di * h1[tid];
}
template<bool I64>
__global__ void fb_agg1(const void* __restrict__ ei, const float* __restrict__ dinv,
                        const float* __restrict__ h1, float* __restrict__ a1,
                        int E, const int* __restrict__ flags) {
    if (flags[FE] != (int)I64) return;
    int tid = blockIdx.x * blockDim.x + threadIdx.x;
    int e = tid >> 4, f = tid & 15;
    if (e >= E) return;
    int s = lde<I64>(ei, (size_t)e);
    int d = lde<I64>(ei, (size_t)E + e);
    float norm = dinv[s] * dinv[d];
    atomicAdd(&a1[(size_t)d * D_HID + f], h1[(size_t)s * D_HID + f] * norm);
}
__global__ void fb_relu_gemm2(const float* __restrict__ a1, const float* __restrict__ W2,
                              float* __restrict__ h2, int n) {
    int node = blockIdx.x * blockDim.x + threadIdx.x;
    if (node >= n) return;
    float c0 = 0.f, c1 = 0.f;
    const float* row = a1 + (size_t)node * D_HID;
#pragma unroll
    for (int f = 0; f < D_HID; ++f) {
        float r = fmaxf(row[f], 0.f);
        c0 += r * W2[f * N_CLS + 0];
        c1 += r * W2[f * N_CLS + 1];
    }
    h2[(size_t)node * 2 + 0] = c0;
    h2[(size_t)node * 2 + 1] = c1;
}
__global__ void fb_a2_init(const float* __restrict__ h2, const float* __restrict__ dinv,
                           const float* __restrict__ b2, float* __restrict__ a2, int n) {
    int tid = blockIdx.x * blockDim.x + threadIdx.x;
    if (tid >= n * N_CLS) return;
    int node = tid >> 1, c = tid & 1;
    float di = dinv[node];
    a2[tid] = b2[c] + di * di * h2[tid];
}
template<bool I64>
__global__ void fb_agg2(const void* __restrict__ ei, const float* __restrict__ dinv,
                        const float* __restrict__ h2, float* __restrict__ a2,
                        int E, const int* __restrict__ flags) {
    if (flags[FE] != (int)I64) return;
    int e = blockIdx.x * blockDim.x + threadIdx.x;
    if (e >= E) return;
    int s = lde<I64>(ei, (size_t)e);
    int d = lde<I64>(ei, (size_t)E + e);
    float norm = dinv[s] * dinv[d];
    atomicAdd(&a2[(size_t)d * 2 + 0], h2[(size_t)s * 2 + 0] * norm);
    atomicAdd(&a2[(size_t)d * 2 + 1], h2[(size_t)s * 2 + 1] * norm);
}
__global__ void fb_gemm1(const float* __restrict__ x, const float* __restrict__ W1,
                         float* __restrict__ h1, int n) {
    __shared__ float w[D_IN * D_HID];
    for (int i = threadIdx.x; i < D_IN * D_HID; i += blockDim.x) w[i] = W1[i];
    __syncthreads();
    int tid = blockIdx.x * blockDim.x + threadIdx.x;
    int node = tid >> 4, f = tid & 15;
    if (node >= n) return;
    const float4* xr = (const float4*)(x + (size_t)node * D_IN);
    float acc = 0.f;
#pragma unroll
    for (int k4 = 0; k4 < D_IN / 4; ++k4) {
        float4 v = xr[k4];
        int k = k4 * 4;
        acc += v.x * w[(k + 0) * D_HID + f];
        acc += v.y * w[(k + 1) * D_HID + f];
        acc += v.z * w[(k + 2) * D_HID + f];
        acc += v.w * w[(k + 3) * D_HID + f];
    }
    h1[tid] = acc;
}
__global__ void fb_lsm(const float* __restrict__ a2, float* __restrict__ out, int n) {
    int node = blockIdx.x * blockDim.x + threadIdx.x;
    if (node >= n) return;
    float v0 = a2[(size_t)node * 2 + 0];
    float v1 = a2[(size_t)node * 2 + 1];
    float m = fmaxf(v0, v1);
    float lse = m + logf(expf(v0 - m) + expf(v1 - m));
    out[(size_t)node * 2 + 0] = v0 - lse;
    out[(size_t)node * 2 + 1] = v1 - lse;
}

extern "C" void kernel_launch(void* const* d_in, const int* in_sizes, int n_in,
                              void* d_out, int out_size, void* d_ws, size_t ws_size,
                              hipStream_t stream) {
    const float* x  = (const float*)d_in[0];
    const void*  ei = d_in[1];
    const float* W1 = (const float*)d_in[2];
    const float* b1 = (const float*)d_in[3];
    const float* W2 = (const float*)d_in[4];
    const float* b2 = (const float*)d_in[5];

    const int N = in_sizes[0] / D_IN;      // 100000
    const int E = in_sizes[1] / 2;         // 3200000
    const int nb = (N + NPB - 1) / NPB;    // 391

    const int B = 256;
    dim3 blk(B);
    const int nBlkN = (N + B - 1) / B;
    const int nBlkE = (E + B - 1) / B;
    char* ws = (char*)d_ws;

    // ---- workspace layout (bytes) ----
    const size_t oDinv  = 0;                                   // N f32
    const size_t oGBcnt = (size_t)N * 4;                       // nb u32
    const size_t oBB    = oGBcnt + (size_t)nb * 4;             // (nb+1) int
    const size_t oGcur  = oBB + (size_t)(nb + 1) * 4;          // nb u32
    const size_t oFlag  = oGcur + (size_t)nb * 4;              // 2 int
    const size_t oStage = (oFlag + 8 + 63) & ~(size_t)63;      // E u32
    const size_t oG1h   = oStage + (size_t)E * 4;              // N*16 half
    const size_t oG2    = oG1h + (size_t)N * D_HID * 2;        // N*2 f32
    const size_t needNew = oG2 + (size_t)N * 2 * 4;            // ~17.3 MB

    if (ws_size >= needNew && nb <= MAXB) {
        float*        dinv   = (float*)(ws + oDinv);
        unsigned int* gbcnt  = (unsigned int*)(ws + oGBcnt);
        int*          bbase  = (int*)(ws + oBB);
        unsigned int* gcur   = (unsigned int*)(ws + oGcur);
        int*          flags  = (int*)(ws + oFlag);
        unsigned int* staged = (unsigned int*)(ws + oStage);
        __half*       g1h    = (__half*)(ws + oG1h);
        float2*       g2     = (float2*)(ws + oG2);

        k_detect<<<dim3(1), blk, 0, stream>>>((const int*)ei, flags);
        hipMemsetAsync(gbcnt, 0, (size_t)nb * 4, stream);

        k_bhist<false><<<dim3(256), blk, 0, stream>>>(ei, gbcnt, E, flags);
        k_bhist<true ><<<dim3(256), blk, 0, stream>>>(ei, gbcnt, E, flags);
        k_bscan<<<dim3(1), dim3(MAXB), 0, stream>>>(gbcnt, bbase, gcur, nb);

        dim3 gPart((E + TILE - 1) / TILE);
        k_part<false><<<gPart, dim3(512), 0, stream>>>(ei, gcur, staged, E, flags);
        k_part<true ><<<gPart, dim3(512), 0, stream>>>(ei, gcur, staged, E, flags);

        k_dinv2<<<dim3(nb), dim3(512), 0, stream>>>(staged, bbase, dinv, N);

        dim3 g_nh((N * D_HID + B - 1) / B);
        k_gemm1h<<<g_nh, blk, 0, stream>>>(x, W1, dinv, g1h, N);
        k_agg1b<<<dim3(nb), dim3(1024), 0, stream>>>(staged, bbase, g1h, dinv, b1, W2, g2, N);
        k_agg2b<<<dim3(nb), dim3(512), 0, stream>>>(staged, bbase, g2, dinv, b2,
                                                    (float2*)d_out, N);
    } else {
        // fallback: round-3 atomic path (needs ~14.8 MB)
        float* dinv  = (float*)(ws + 0);
        float* h1    = (float*)(ws + 400128);
        float* a1    = (float*)(ws + 6800256);
        float* h2    = (float*)(ws + 13200384);
        float* a2    = (float*)(ws + 14000512);
        int*   flags = (int*)  (ws + 14800640);

        k_detect<<<dim3(1), blk, 0, stream>>>((const int*)ei, flags);
        fb_deg_init<<<dim3(nBlkN), blk, 0, stream>>>((unsigned int*)dinv, N);
        fb_deg_count<false><<<dim3(nBlkE), blk, 0, stream>>>(ei, (unsigned int*)dinv, E, flags);
        fb_deg_count<true ><<<dim3(nBlkE), blk, 0, stream>>>(ei, (unsigned int*)dinv, E, flags);
        fb_dinv_inplace<<<dim3(nBlkN), blk, 0, stream>>>(dinv, N);

        dim3 g_nh((N * D_HID + B - 1) / B);
        fb_gemm1<<<g_nh, blk, 0, stream>>>(x, W1, h1, N);
        fb_a1_init<<<g_nh, blk, 0, stream>>>(h1, dinv, b1, a1, N);
        dim3 g_eh(((size_t)E * D_HID + B - 1) / B);
        fb_agg1<false><<<g_eh, blk, 0, stream>>>(ei, dinv, h1, a1, E, flags);
        fb_agg1<true ><<<g_eh, blk, 0, stream>>>(ei, dinv, h1, a1, E, flags);
        fb_relu_gemm2<<<dim3(nBlkN), blk, 0, stream>>>(a1, W2, h2, N);
        dim3 g_n2((N * N_CLS + B - 1) / B);
        fb_a2_init<<<g_n2, blk, 0, stream>>>(h2, dinv, b2, a2, N);
        fb_agg2<false><<<dim3(nBlkE), blk, 0, stream>>>(ei, dinv, h2, a2, E, flags);
        fb_agg2<true ><<<dim3(nBlkE), blk, 0, stream>>>(ei, dinv, h2, a2, E, flags);
        fb_lsm<<<dim3(nBlkN), blk, 0, stream>>>(a2, (float*)d_out, N);
    }
}

// Round 11
// 255.305 us; speedup vs baseline: 2.2398x; 1.0594x over previous
//
#include <hip/hip_runtime.h>
#include <hip/hip_bf16.h>
#include <hip/hip_fp16.h>

#define D_IN  128
#define D_HID 16
#define N_CLS 2
#define NPB   256          // nodes per bucket (bucket = dst >> 8)
#define MAXB  512          // max buckets (N <= 131072)
#define TILE  8192         // edges per k_part workgroup
#define FPSCALE 65536.0f   // Q15.16 fixed-point scale for LDS int accumulation
#define FPINV   (1.0f / 65536.0f)

#define FE 0   // edge_index storage: 0 = int32, 1 = int64

// ---------------- edge dtype detection (1 block) ----------------
__global__ void k_detect(const int* __restrict__ ev, int* __restrict__ flags) {
    __shared__ int sE;
    if (threadIdx.x == 0) sE = 0;
    __syncthreads();
    if (ev[2 * threadIdx.x + 1] != 0) atomicOr(&sE, 1);
    __syncthreads();
    if (threadIdx.x == 0) flags[FE] = sE ? 0 : 1;
}

template<bool I64>
__device__ __forceinline__ int lde(const void* p, size_t i) {
    if constexpr (I64) return (int)((const long long*)p)[i];
    else               return ((const int*)p)[i];
}

// ---------------- bucket histogram (LDS-privatized, grid-stride, runtime dtype) ----------------
__global__ void k_bhist(const void* __restrict__ ei, unsigned int* __restrict__ gbcnt,
                        int E, const int* __restrict__ flags) {
    __shared__ unsigned int h[MAXB];
    for (int i = threadIdx.x; i < MAXB; i += blockDim.x) h[i] = 0u;
    __syncthreads();
    int stride = gridDim.x * blockDim.x;
    if (flags[FE]) {
        for (int e = blockIdx.x * blockDim.x + threadIdx.x; e < E; e += stride)
            atomicAdd(&h[lde<true>(ei, (size_t)E + e) >> 8], 1u);
    } else {
        for (int e = blockIdx.x * blockDim.x + threadIdx.x; e < E; e += stride)
            atomicAdd(&h[lde<false>(ei, (size_t)E + e) >> 8], 1u);
    }
    __syncthreads();
    for (int i = threadIdx.x; i < MAXB; i += blockDim.x)
        if (h[i]) atomicAdd(&gbcnt[i], h[i]);
}

// ---------------- bucket scan: bbase (exclusive) + cursor init ----------------
__global__ void k_bscan(const unsigned int* __restrict__ gbcnt, int* __restrict__ bbase,
                        unsigned int* __restrict__ gcur, int nb) {
    __shared__ int s[MAXB];
    int tid = threadIdx.x;
    int v = (tid < nb) ? (int)gbcnt[tid] : 0;
    s[tid] = v;
    __syncthreads();
#pragma unroll
    for (int off = 1; off < MAXB; off <<= 1) {
        int t = (tid >= off) ? s[tid - off] : 0;
        __syncthreads();
        s[tid] += t;
        __syncthreads();
    }
    int excl = s[tid] - v;
    if (tid <= nb) bbase[tid] = (tid < nb) ? excl : s[nb - 1];  // bbase[nb] = total
    if (tid < nb)  gcur[tid] = (unsigned int)excl;
}

// ---------------- pass 1: LDS-staged partition by bucket (runtime dtype) ----------------
template<bool I64>
__device__ __forceinline__ void part_body(
        const void* __restrict__ ei, unsigned int* __restrict__ gcur,
        unsigned int* __restrict__ staged, int E,
        unsigned int* sbuf, unsigned short* bbuf,
        int* hist, int* scn, int* lbase, int* gb) {
    int tid = threadIdx.x;
    int t0 = blockIdx.x * TILE;

    hist[tid] = 0;
    __syncthreads();

    int myB[16]; unsigned int myP[16]; int myR[16];
#pragma unroll
    for (int k = 0; k < 16; ++k) {
        int e = t0 + k * 512 + tid;
        if (e < E) {
            int s = lde<I64>(ei, (size_t)e);
            int d = lde<I64>(ei, (size_t)E + e);
            int b = d >> 8;
            myB[k] = b;
            myP[k] = ((unsigned int)s << 8) | (unsigned int)(d & 255);
            myR[k] = atomicAdd(&hist[b], 1);
        } else myB[k] = -1;
    }
    __syncthreads();

    int v = hist[tid];
    scn[tid] = v;
    __syncthreads();
#pragma unroll
    for (int off = 1; off < MAXB; off <<= 1) {
        int t = (tid >= off) ? scn[tid - off] : 0;
        __syncthreads();
        scn[tid] += t;
        __syncthreads();
    }
    int excl = scn[tid] - v;
    lbase[tid] = excl;
    int gb_ = 0;
    if (v > 0) gb_ = (int)atomicAdd(&gcur[tid], (unsigned int)v);
    gb[tid] = gb_;
    __syncthreads();

#pragma unroll
    for (int k = 0; k < 16; ++k) {
        if (myB[k] >= 0) {
            int pos = lbase[myB[k]] + myR[k];
            sbuf[pos] = myP[k];
            bbuf[pos] = (unsigned short)myB[k];
        }
    }
    __syncthreads();

    int tot = scn[MAXB - 1];
    for (int i = tid; i < tot; i += 512) {
        int b = bbuf[i];
        staged[(size_t)gb[b] + (i - lbase[b])] = sbuf[i];  // ~84B contiguous runs
    }
}

__global__ __launch_bounds__(512) void k_part(
        const void* __restrict__ ei, unsigned int* __restrict__ gcur,
        unsigned int* __restrict__ staged, int E, const int* __restrict__ flags) {
    __shared__ unsigned int sbuf[TILE];       // 32 KB
    __shared__ unsigned short bbuf[TILE];     // 16 KB
    __shared__ int hist[MAXB], scn[MAXB], lbase[MAXB], gb[MAXB];  // 8 KB
    if (flags[FE]) part_body<true >(ei, gcur, staged, E, sbuf, bbuf, hist, scn, lbase, gb);
    else           part_body<false>(ei, gcur, staged, E, sbuf, bbuf, hist, scn, lbase, gb);
}

// ---------------- per-bucket degree -> dinv (ILP x8) ----------------
__global__ __launch_bounds__(512) void k_dinv2(
        const unsigned int* __restrict__ staged, const int* __restrict__ bbase,
        float* __restrict__ dinv, int N) {
    __shared__ unsigned int h[NPB];
    int tid = threadIdx.x, b = blockIdx.x;
    int s0 = bbase[b], cnt = bbase[b + 1] - s0;
    if (tid < NPB) h[tid] = 0u;
    __syncthreads();
    for (int j0 = tid * 8; j0 < cnt; j0 += 4096) {
        int jm = cnt - j0; if (jm > 8) jm = 8;
        unsigned int p[8];
#pragma unroll
        for (int i = 0; i < 8; ++i) if (i < jm) p[i] = staged[(size_t)s0 + j0 + i];
#pragma unroll
        for (int i = 0; i < 8; ++i) if (i < jm) atomicAdd(&h[p[i] & 255], 1u);
    }
    __syncthreads();
    int base = b * NPB, nn = N - base; if (nn > NPB) nn = NPB;
    if (tid < nn) dinv[base + tid] = rsqrtf((float)(h[tid] + 1u));  // +1 self loop
}

// ---------------- layer 1 GEMM: g1h = (half)(dinv * (x @ W1)) ----------------
__global__ void k_gemm1h(const float* __restrict__ x, const float* __restrict__ W1,
                         const float* __restrict__ dinv, __half* __restrict__ g1h, int n) {
    __shared__ float w[D_IN * D_HID];  // 8 KiB
    for (int i = threadIdx.x; i < D_IN * D_HID; i += blockDim.x)
        w[i] = W1[i];
    __syncthreads();
    int tid = blockIdx.x * blockDim.x + threadIdx.x;
    int node = tid >> 4, f = tid & 15;
    if (node >= n) return;
    const float4* xr = (const float4*)(x + (size_t)node * D_IN);
    float acc = 0.f;
#pragma unroll
    for (int k4 = 0; k4 < D_IN / 4; ++k4) {
        float4 v = xr[k4];
        int k = k4 * 4;
        acc += v.x * w[(k + 0) * D_HID + f];
        acc += v.y * w[(k + 1) * D_HID + f];
        acc += v.z * w[(k + 2) * D_HID + f];
        acc += v.w * w[(k + 3) * D_HID + f];
    }
    g1h[tid] = __float2half(dinv[node] * acc);
}

// ---------------- bucket-major agg1 (Q15.16 LDS int atomics, ILP x8) ----------------
__global__ __launch_bounds__(1024) void k_agg1b(
        const unsigned int* __restrict__ staged, const int* __restrict__ bbase,
        const __half* __restrict__ g1h, const float* __restrict__ dinv,
        const float* __restrict__ b1, const float* __restrict__ W2,
        float2* __restrict__ g2, int N) {
    __shared__ int accI[NPB * D_HID];   // 16 KB
    int tid = threadIdx.x, b = blockIdx.x;
    int s0 = bbase[b], cnt = bbase[b + 1] - s0;
    int base = b * NPB;
    for (int i = tid; i < NPB * D_HID; i += 1024) accI[i] = 0;
    __syncthreads();
    int f = tid & 15;
    int gid = tid >> 4;   // 0..63
    for (int j0 = gid * 8; j0 < cnt; j0 += 512) {
        int jm = cnt - j0; if (jm > 8) jm = 8;
        unsigned int p[8]; float v[8];
#pragma unroll
        for (int i = 0; i < 8; ++i) if (i < jm) p[i] = staged[(size_t)s0 + j0 + i];
#pragma unroll
        for (int i = 0; i < 8; ++i) if (i < jm)
            v[i] = __half2float(g1h[(size_t)(p[i] >> 8) * D_HID + f]);
#pragma unroll
        for (int i = 0; i < 8; ++i) if (i < jm)
            atomicAdd(&accI[(int)(p[i] & 255) * D_HID + f], __float2int_rn(v[i] * FPSCALE));
    }
    __syncthreads();
    int nn = N - base; if (nn > NPB) nn = NPB;
    for (int n = gid; n < nn; n += 64) {
        int gn = base + n;
        float acc = (float)accI[n * D_HID + f] * FPINV
                  + __half2float(g1h[(size_t)gn * D_HID + f]);   // + self loop
        float di = dinv[gn];
        float r = fmaxf(b1[f] + di * acc, 0.f);
        float c0 = r * W2[f * N_CLS + 0];
        float c1 = r * W2[f * N_CLS + 1];
#pragma unroll
        for (int m = 8; m >= 1; m >>= 1) {
            c0 += __shfl_xor(c0, m, 64);
            c1 += __shfl_xor(c1, m, 64);
        }
        if (f == 0) g2[gn] = make_float2(di * c0, di * c1);
    }
}

// ---------------- bucket-major agg2 (Q15.16 LDS int atomics, ILP x4) + log_softmax ----------------
__global__ __launch_bounds__(512) void k_agg2b(
        const unsigned int* __restrict__ staged, const int* __restrict__ bbase,
        const float2* __restrict__ g2, const float* __restrict__ dinv,
        const float* __restrict__ b2, float2* __restrict__ out, int N) {
    __shared__ int accI[NPB * 2];   // 2 KB
    int tid = threadIdx.x, b = blockIdx.x;
    int s0 = bbase[b], cnt = bbase[b + 1] - s0;
    int base = b * NPB;
    for (int i = tid; i < NPB * 2; i += 512) accI[i] = 0;
    __syncthreads();
    for (int j0 = tid * 4; j0 < cnt; j0 += 2048) {
        int jm = cnt - j0; if (jm > 4) jm = 4;
        unsigned int p[4]; float2 t[4];
#pragma unroll
        for (int i = 0; i < 4; ++i) if (i < jm) p[i] = staged[(size_t)s0 + j0 + i];
#pragma unroll
        for (int i = 0; i < 4; ++i) if (i < jm) t[i] = g2[p[i] >> 8];
#pragma unroll
        for (int i = 0; i < 4; ++i) if (i < jm) {
            int dl = (int)(p[i] & 255);
            atomicAdd(&accI[dl * 2 + 0], __float2int_rn(t[i].x * FPSCALE));
            atomicAdd(&accI[dl * 2 + 1], __float2int_rn(t[i].y * FPSCALE));
        }
    }
    __syncthreads();
    int nn = N - base; if (nn > NPB) nn = NPB;
    for (int n = tid; n < nn; n += 512) {
        int gn = base + n;
        float2 self = g2[gn];
        float di = dinv[gn];
        float v0 = b2[0] + di * ((float)accI[n * 2 + 0] * FPINV + self.x);
        float v1 = b2[1] + di * ((float)accI[n * 2 + 1] * FPINV + self.y);
        float mx = fmaxf(v0, v1);
        float lse = mx + logf(expf(v0 - mx) + expf(v1 - mx));
        out[gn] = make_float2(v0 - lse, v1 - lse);
    }
}

// =================== fallback (round-3 atomic path, if ws too small) ===================
__global__ void fb_deg_init(unsigned int* __restrict__ deg, int n) {
    int i = blockIdx.x * blockDim.x + threadIdx.x;
    if (i < n) deg[i] = 1u;
}
template<bool I64>
__global__ void fb_deg_count(const void* __restrict__ ei, unsigned int* __restrict__ deg,
                             int E, const int* __restrict__ flags) {
    if (flags[FE] != (int)I64) return;
    int e = blockIdx.x * blockDim.x + threadIdx.x;
    if (e < E) atomicAdd(&deg[lde<I64>(ei, (size_t)E + e)], 1u);
}
__global__ void fb_dinv_inplace(float* __restrict__ dinv, int n) {
    int i = blockIdx.x * blockDim.x + threadIdx.x;
    if (i < n) {
        unsigned int u = ((const unsigned int*)dinv)[i];
        dinv[i] = rsqrtf((float)u);
    }
}
__global__ void fb_a1_init(const float* __restrict__ h1, const float* __restrict__ dinv,
                           const float* __restrict__ b1, float* __restrict__ a1, int n) {
    int tid = blockIdx.x * blockDim.x + threadIdx.x;
    if (tid >= n * D_HID) return;
    int node = tid >> 4, f = tid & 15;
    float di = dinv[node];
    a1[tid] = b1[f] + di * di * h1[tid];
}
template<bool I64>
__global__ void fb_agg1(const void* __restrict__ ei, const float* __restrict__ dinv,
                        const float* __restrict__ h1, float* __restrict__ a1,
                        int E, const int* __restrict__ flags) {
    if (flags[FE] != (int)I64) return;
    int tid = blockIdx.x * blockDim.x + threadIdx.x;
    int e = tid >> 4, f = tid & 15;
    if (e >= E) return;
    int s = lde<I64>(ei, (size_t)e);
    int d = lde<I64>(ei, (size_t)E + e);
    float norm = dinv[s] * dinv[d];
    atomicAdd(&a1[(size_t)d * D_HID + f], h1[(size_t)s * D_HID + f] * norm);
}
__global__ void fb_relu_gemm2(const float* __restrict__ a1, const float* __restrict__ W2,
                              float* __restrict__ h2, int n) {
    int node = blockIdx.x * blockDim.x + threadIdx.x;
    if (node >= n) return;
    float c0 = 0.f, c1 = 0.f;
    const float* row = a1 + (size_t)node * D_HID;
#pragma unroll
    for (int f = 0; f < D_HID; ++f) {
        float r = fmaxf(row[f], 0.f);
        c0 += r * W2[f * N_CLS + 0];
        c1 += r * W2[f * N_CLS + 1];
    }
    h2[(size_t)node * 2 + 0] = c0;
    h2[(size_t)node * 2 + 1] = c1;
}
__global__ void fb_a2_init(const float* __restrict__ h2, const float* __restrict__ dinv,
                           const float* __restrict__ b2, float* __restrict__ a2, int n) {
    int tid = blockIdx.x * blockDim.x + threadIdx.x;
    if (tid >= n * N_CLS) return;
    int node = tid >> 1, c = tid & 1;
    float di = dinv[node];
    a2[tid] = b2[c] + di * di * h2[tid];
}
template<bool I64>
__global__ void fb_agg2(const void* __restrict__ ei, const float* __restrict__ dinv,
                        const float* __restrict__ h2, float* __restrict__ a2,
                        int E, const int* __restrict__ flags) {
    if (flags[FE] != (int)I64) return;
    int e = blockIdx.x * blockDim.x + threadIdx.x;
    if (e >= E) return;
    int s = lde<I64>(ei, (size_t)e);
    int d = lde<I64>(ei, (size_t)E + e);
    float norm = dinv[s] * dinv[d];
    atomicAdd(&a2[(size_t)d * 2 + 0], h2[(size_t)s * 2 + 0] * norm);
    atomicAdd(&a2[(size_t)d * 2 + 1], h2[(size_t)s * 2 + 1] * norm);
}
__global__ void fb_gemm1(const float* __restrict__ x, const float* __restrict__ W1,
                         float* __restrict__ h1, int n) {
    __shared__ float w[D_IN * D_HID];
    for (int i = threadIdx.x; i < D_IN * D_HID; i += blockDim.x) w[i] = W1[i];
    __syncthreads();
    int tid = blockIdx.x * blockDim.x + threadIdx.x;
    int node = tid >> 4, f = tid & 15;
    if (node >= n) return;
    const float4* xr = (const float4*)(x + (size_t)node * D_IN);
    float acc = 0.f;
#pragma unroll
    for (int k4 = 0; k4 < D_IN / 4; ++k4) {
        float4 v = xr[k4];
        int k = k4 * 4;
        acc += v.x * w[(k + 0) * D_HID + f];
        acc += v.y * w[(k + 1) * D_HID + f];
        acc += v.z * w[(k + 2) * D_HID + f];
        acc += v.w * w[(k + 3) * D_HID + f];
    }
    h1[tid] = acc;
}
__global__ void fb_lsm(const float* __restrict__ a2, float* __restrict__ out, int n) {
    int node = blockIdx.x * blockDim.x + threadIdx.x;
    if (node >= n) return;
    float v0 = a2[(size_t)node * 2 + 0];
    float v1 = a2[(size_t)node * 2 + 1];
    float m = fmaxf(v0, v1);
    float lse = m + logf(expf(v0 - m) + expf(v1 - m));
    out[(size_t)node * 2 + 0] = v0 - lse;
    out[(size_t)node * 2 + 1] = v1 - lse;
}

extern "C" void kernel_launch(void* const* d_in, const int* in_sizes, int n_in,
                              void* d_out, int out_size, void* d_ws, size_t ws_size,
                              hipStream_t stream) {
    const float* x  = (const float*)d_in[0];
    const void*  ei = d_in[1];
    const float* W1 = (const float*)d_in[2];
    const float* b1 = (const float*)d_in[3];
    const float* W2 = (const float*)d_in[4];
    const float* b2 = (const float*)d_in[5];

    const int N = in_sizes[0] / D_IN;      // 100000
    const int E = in_sizes[1] / 2;         // 3200000
    const int nb = (N + NPB - 1) / NPB;    // 391

    const int B = 256;
    dim3 blk(B);
    const int nBlkN = (N + B - 1) / B;
    const int nBlkE = (E + B - 1) / B;
    char* ws = (char*)d_ws;

    // ---- workspace layout (bytes) ----
    const size_t oDinv  = 0;                                   // N f32
    const size_t oGBcnt = (size_t)N * 4;                       // nb u32
    const size_t oBB    = oGBcnt + (size_t)nb * 4;             // (nb+1) int
    const size_t oGcur  = oBB + (size_t)(nb + 1) * 4;          // nb u32
    const size_t oFlag  = oGcur + (size_t)nb * 4;              // 2 int
    const size_t oStage = (oFlag + 8 + 63) & ~(size_t)63;      // E u32
    const size_t oG1h   = oStage + (size_t)E * 4;              // N*16 half
    const size_t oG2    = oG1h + (size_t)N * D_HID * 2;        // N*2 f32
    const size_t needNew = oG2 + (size_t)N * 2 * 4;            // ~17.3 MB

    if (ws_size >= needNew && nb <= MAXB) {
        float*        dinv   = (float*)(ws + oDinv);
        unsigned int* gbcnt  = (unsigned int*)(ws + oGBcnt);
        int*          bbase  = (int*)(ws + oBB);
        unsigned int* gcur   = (unsigned int*)(ws + oGcur);
        int*          flags  = (int*)(ws + oFlag);
        unsigned int* staged = (unsigned int*)(ws + oStage);
        __half*       g1h    = (__half*)(ws + oG1h);
        float2*       g2     = (float2*)(ws + oG2);

        k_detect<<<dim3(1), blk, 0, stream>>>((const int*)ei, flags);
        hipMemsetAsync(gbcnt, 0, (size_t)nb * 4, stream);

        k_bhist<<<dim3(256), blk, 0, stream>>>(ei, gbcnt, E, flags);
        k_bscan<<<dim3(1), dim3(MAXB), 0, stream>>>(gbcnt, bbase, gcur, nb);

        dim3 gPart((E + TILE - 1) / TILE);
        k_part<<<gPart, dim3(512), 0, stream>>>(ei, gcur, staged, E, flags);

        k_dinv2<<<dim3(nb), dim3(512), 0, stream>>>(staged, bbase, dinv, N);

        dim3 g_nh((N * D_HID + B - 1) / B);
        k_gemm1h<<<g_nh, blk, 0, stream>>>(x, W1, dinv, g1h, N);
        k_agg1b<<<dim3(nb), dim3(1024), 0, stream>>>(staged, bbase, g1h, dinv, b1, W2, g2, N);
        k_agg2b<<<dim3(nb), dim3(512), 0, stream>>>(staged, bbase, g2, dinv, b2,
                                                    (float2*)d_out, N);
    } else {
        // fallback: round-3 atomic path (needs ~14.8 MB)
        float* dinv  = (float*)(ws + 0);
        float* h1    = (float*)(ws + 400128);
        float* a1    = (float*)(ws + 6800256);
        float* h2    = (float*)(ws + 13200384);
        float* a2    = (float*)(ws + 14000512);
        int*   flags = (int*)  (ws + 14800640);

        k_detect<<<dim3(1), blk, 0, stream>>>((const int*)ei, flags);
        fb_deg_init<<<dim3(nBlkN), blk, 0, stream>>>((unsigned int*)dinv, N);
        fb_deg_count<false><<<dim3(nBlkE), blk, 0, stream>>>(ei, (unsigned int*)dinv, E, flags);
        fb_deg_count<true ><<<dim3(nBlkE), blk, 0, stream>>>(ei, (unsigned int*)dinv, E, flags);
        fb_dinv_inplace<<<dim3(nBlkN), blk, 0, stream>>>(dinv, N);

        dim3 g_nh((N * D_HID + B - 1) / B);
        fb_gemm1<<<g_nh, blk, 0, stream>>>(x, W1, h1, N);
        fb_a1_init<<<g_nh, blk, 0, stream>>>(h1, dinv, b1, a1, N);
        dim3 g_eh(((size_t)E * D_HID + B - 1) / B);
        fb_agg1<false><<<g_eh, blk, 0, stream>>>(ei, dinv, h1, a1, E, flags);
        fb_agg1<true ><<<g_eh, blk, 0, stream>>>(ei, dinv, h1, a1, E, flags);
        fb_relu_gemm2<<<dim3(nBlkN), blk, 0, stream>>>(a1, W2, h2, N);
        dim3 g_n2((N * N_CLS + B - 1) / B);
        fb_a2_init<<<g_n2, blk, 0, stream>>>(h2, dinv, b2, a2, N);
        fb_agg2<false><<<dim3(nBlkE), blk, 0, stream>>>(ei, dinv, h2, a2, E, flags);
        fb_agg2<true ><<<dim3(nBlkE), blk, 0, stream>>>(ei, dinv, h2, a2, E, flags);
        fb_lsm<<<dim3(nBlkN), blk, 0, stream>>>(a2, (float*)d_out, N);
    }
}

// Round 12
// 238.541 us; speedup vs baseline: 2.3972x; 1.0703x over previous
//
#include <hip/hip_runtime.h>
#include <hip/hip_bf16.h>
#include <hip/hip_fp16.h>

#define D_IN  128
#define D_HID 16
#define N_CLS 2
#define NPB   256          // nodes per bucket (bucket = dst >> 8)
#define MAXB  512          // max buckets (N <= 131072)
#define TILE  8192         // edges per k_part workgroup
#define FPSCALE 65536.0f   // Q15.16 fixed-point scale for LDS int accumulation
#define FPINV   (1.0f / 65536.0f)

#define FE 0   // edge_index storage: 0 = int32, 1 = int64

// ---------------- edge dtype detection (1 block) ----------------
__global__ void k_detect(const int* __restrict__ ev, int* __restrict__ flags) {
    __shared__ int sE;
    if (threadIdx.x == 0) sE = 0;
    __syncthreads();
    if (ev[2 * threadIdx.x + 1] != 0) atomicOr(&sE, 1);
    __syncthreads();
    if (threadIdx.x == 0) flags[FE] = sE ? 0 : 1;
}

template<bool I64>
__device__ __forceinline__ int lde(const void* p, size_t i) {
    if constexpr (I64) return (int)((const long long*)p)[i];
    else               return ((const int*)p)[i];
}

// ---------------- bucket histogram (LDS-privatized, grid-stride, runtime dtype) ----------------
__global__ void k_bhist(const void* __restrict__ ei, unsigned int* __restrict__ gbcnt,
                        int E, const int* __restrict__ flags) {
    __shared__ unsigned int h[MAXB];
    for (int i = threadIdx.x; i < MAXB; i += blockDim.x) h[i] = 0u;
    __syncthreads();
    int stride = gridDim.x * blockDim.x;
    if (flags[FE]) {
        for (int e = blockIdx.x * blockDim.x + threadIdx.x; e < E; e += stride)
            atomicAdd(&h[lde<true>(ei, (size_t)E + e) >> 8], 1u);
    } else {
        for (int e = blockIdx.x * blockDim.x + threadIdx.x; e < E; e += stride)
            atomicAdd(&h[lde<false>(ei, (size_t)E + e) >> 8], 1u);
    }
    __syncthreads();
    for (int i = threadIdx.x; i < MAXB; i += blockDim.x)
        if (h[i]) atomicAdd(&gbcnt[i], h[i]);
}

// ---------------- bucket scan: bbase (exclusive) + cursor init ----------------
__global__ void k_bscan(const unsigned int* __restrict__ gbcnt, int* __restrict__ bbase,
                        unsigned int* __restrict__ gcur, int nb) {
    __shared__ int s[MAXB];
    int tid = threadIdx.x;
    int v = (tid < nb) ? (int)gbcnt[tid] : 0;
    s[tid] = v;
    __syncthreads();
#pragma unroll
    for (int off = 1; off < MAXB; off <<= 1) {
        int t = (tid >= off) ? s[tid - off] : 0;
        __syncthreads();
        s[tid] += t;
        __syncthreads();
    }
    int excl = s[tid] - v;
    if (tid <= nb) bbase[tid] = (tid < nb) ? excl : s[nb - 1];  // bbase[nb] = total
    if (tid < nb)  gcur[tid] = (unsigned int)excl;
}

// ---------------- pass 1: LDS-staged partition by bucket (runtime dtype) ----------------
template<bool I64>
__device__ __forceinline__ void part_body(
        const void* __restrict__ ei, unsigned int* __restrict__ gcur,
        unsigned int* __restrict__ staged, int E,
        unsigned int* sbuf, unsigned short* bbuf,
        int* hist, int* scn, int* lbase, int* gb) {
    int tid = threadIdx.x;
    int t0 = blockIdx.x * TILE;

    hist[tid] = 0;
    __syncthreads();

    int myB[16]; unsigned int myP[16]; int myR[16];
#pragma unroll
    for (int k = 0; k < 16; ++k) {
        int e = t0 + k * 512 + tid;
        if (e < E) {
            int s = lde<I64>(ei, (size_t)e);
            int d = lde<I64>(ei, (size_t)E + e);
            int b = d >> 8;
            myB[k] = b;
            myP[k] = ((unsigned int)s << 8) | (unsigned int)(d & 255);
            myR[k] = atomicAdd(&hist[b], 1);
        } else myB[k] = -1;
    }
    __syncthreads();

    int v = hist[tid];
    scn[tid] = v;
    __syncthreads();
#pragma unroll
    for (int off = 1; off < MAXB; off <<= 1) {
        int t = (tid >= off) ? scn[tid - off] : 0;
        __syncthreads();
        scn[tid] += t;
        __syncthreads();
    }
    int excl = scn[tid] - v;
    lbase[tid] = excl;
    int gb_ = 0;
    if (v > 0) gb_ = (int)atomicAdd(&gcur[tid], (unsigned int)v);
    gb[tid] = gb_;
    __syncthreads();

#pragma unroll
    for (int k = 0; k < 16; ++k) {
        if (myB[k] >= 0) {
            int pos = lbase[myB[k]] + myR[k];
            sbuf[pos] = myP[k];
            bbuf[pos] = (unsigned short)myB[k];
        }
    }
    __syncthreads();

    int tot = scn[MAXB - 1];
    for (int i = tid; i < tot; i += 512) {
        int b = bbuf[i];
        staged[(size_t)gb[b] + (i - lbase[b])] = sbuf[i];  // ~84B contiguous runs
    }
}

__global__ __launch_bounds__(512) void k_part(
        const void* __restrict__ ei, unsigned int* __restrict__ gcur,
        unsigned int* __restrict__ staged, int E, const int* __restrict__ flags) {
    __shared__ unsigned int sbuf[TILE];       // 32 KB
    __shared__ unsigned short bbuf[TILE];     // 16 KB
    __shared__ int hist[MAXB], scn[MAXB], lbase[MAXB], gb[MAXB];  // 8 KB
    if (flags[FE]) part_body<true >(ei, gcur, staged, E, sbuf, bbuf, hist, scn, lbase, gb);
    else           part_body<false>(ei, gcur, staged, E, sbuf, bbuf, hist, scn, lbase, gb);
}

// ---------------- per-bucket degree -> dinv (ILP x8) ----------------
__global__ __launch_bounds__(512) void k_dinv2(
        const unsigned int* __restrict__ staged, const int* __restrict__ bbase,
        float* __restrict__ dinv, int N) {
    __shared__ unsigned int h[NPB];
    int tid = threadIdx.x, b = blockIdx.x;
    int s0 = bbase[b], cnt = bbase[b + 1] - s0;
    if (tid < NPB) h[tid] = 0u;
    __syncthreads();
    for (int j0 = tid * 8; j0 < cnt; j0 += 4096) {
        int jm = cnt - j0; if (jm > 8) jm = 8;
        unsigned int p[8];
#pragma unroll
        for (int i = 0; i < 8; ++i) if (i < jm) p[i] = staged[(size_t)s0 + j0 + i];
#pragma unroll
        for (int i = 0; i < 8; ++i) if (i < jm) atomicAdd(&h[p[i] & 255], 1u);
    }
    __syncthreads();
    int base = b * NPB, nn = N - base; if (nn > NPB) nn = NPB;
    if (tid < nn) dinv[base + tid] = rsqrtf((float)(h[tid] + 1u));  // +1 self loop
}

// ---------------- layer 1 GEMM: g1h = (half)(dinv * (x @ W1)) ----------------
// Transposed W in LDS (padded rows: 2-way banks = free), ds_read_b128, 4 nodes/thread.
__global__ __launch_bounds__(256) void k_gemm1x(
        const float* __restrict__ x, const float* __restrict__ W1,
        const float* __restrict__ dinv, __half* __restrict__ g1h, int n) {
    __shared__ float wT[16][132];   // +4 pad: row f starts at bank 4f%32
    int tid = threadIdx.x;
    for (int i = tid; i < D_IN * D_HID; i += 256) {
        int f = i >> 7, k = i & 127;
        wT[f][k] = W1[k * D_HID + f];
    }
    __syncthreads();
    int f = tid & 15, q = tid >> 4;          // 16 quads/block
    int nb0 = blockIdx.x * 64 + q * 4;       // 4 nodes per thread
    if (nb0 >= n) return;
    const float* wr = &wT[f][0];
    const float* xb = x + (size_t)nb0 * D_IN;
    float a0 = 0.f, a1 = 0.f, a2 = 0.f, a3 = 0.f;
    if (nb0 + 4 <= n) {
#pragma unroll 8
        for (int k4 = 0; k4 < 32; ++k4) {
            float4 w4 = *(const float4*)(wr + k4 * 4);
            float4 x0 = *(const float4*)(xb + 0 * D_IN + k4 * 4);
            float4 x1 = *(const float4*)(xb + 1 * D_IN + k4 * 4);
            float4 x2 = *(const float4*)(xb + 2 * D_IN + k4 * 4);
            float4 x3 = *(const float4*)(xb + 3 * D_IN + k4 * 4);
            a0 += x0.x * w4.x + x0.y * w4.y + x0.z * w4.z + x0.w * w4.w;
            a1 += x1.x * w4.x + x1.y * w4.y + x1.z * w4.z + x1.w * w4.w;
            a2 += x2.x * w4.x + x2.y * w4.y + x2.z * w4.z + x2.w * w4.w;
            a3 += x3.x * w4.x + x3.y * w4.y + x3.z * w4.z + x3.w * w4.w;
        }
        g1h[(size_t)(nb0 + 0) * D_HID + f] = __float2half(dinv[nb0 + 0] * a0);
        g1h[(size_t)(nb0 + 1) * D_HID + f] = __float2half(dinv[nb0 + 1] * a1);
        g1h[(size_t)(nb0 + 2) * D_HID + f] = __float2half(dinv[nb0 + 2] * a2);
        g1h[(size_t)(nb0 + 3) * D_HID + f] = __float2half(dinv[nb0 + 3] * a3);
    } else {
        int m = n - nb0;   // 1..3 (tail block)
        for (int k4 = 0; k4 < 32; ++k4) {
            float4 w4 = *(const float4*)(wr + k4 * 4);
            for (int j = 0; j < m; ++j) {
                float4 xv = *(const float4*)(xb + j * D_IN + k4 * 4);
                float s = xv.x * w4.x + xv.y * w4.y + xv.z * w4.z + xv.w * w4.w;
                if (j == 0) a0 += s; else if (j == 1) a1 += s; else a2 += s;
            }
        }
        for (int j = 0; j < m; ++j) {
            float aj = (j == 0) ? a0 : ((j == 1) ? a1 : a2);
            g1h[(size_t)(nb0 + j) * D_HID + f] = __float2half(dinv[nb0 + j] * aj);
        }
    }
}

// ---------------- bucket-major agg1 (Q15.16 LDS int atomics, half2, ILP x8) ----------------
__global__ __launch_bounds__(1024) void k_agg1b(
        const unsigned int* __restrict__ staged, const int* __restrict__ bbase,
        const __half* __restrict__ g1h, const float* __restrict__ dinv,
        const float* __restrict__ b1, const float* __restrict__ W2,
        float2* __restrict__ g2, int N) {
    __shared__ int accI[NPB * D_HID];   // 16 KB
    int tid = threadIdx.x, b = blockIdx.x;
    int s0 = bbase[b], cnt = bbase[b + 1] - s0;
    int base = b * NPB;
    for (int i = tid; i < NPB * D_HID; i += 1024) accI[i] = 0;
    __syncthreads();
    const __half2* g1h2 = (const __half2*)g1h;
    int f2 = tid & 7;          // feature pair 0..7
    int eg = tid >> 3;         // edge group 0..127
    for (int j0 = eg * 8; j0 < cnt; j0 += 1024) {
        int jm = cnt - j0; if (jm > 8) jm = 8;
        unsigned int p[8]; float2 v[8];
#pragma unroll
        for (int i = 0; i < 8; ++i) if (i < jm) p[i] = staged[(size_t)s0 + j0 + i];
#pragma unroll
        for (int i = 0; i < 8; ++i) if (i < jm)
            v[i] = __half22float2(g1h2[(size_t)(p[i] >> 8) * 8 + f2]);
#pragma unroll
        for (int i = 0; i < 8; ++i) if (i < jm) {
            int a = (int)(p[i] & 255) * D_HID + f2 * 2;
            atomicAdd(&accI[a + 0], __float2int_rn(v[i].x * FPSCALE));
            atomicAdd(&accI[a + 1], __float2int_rn(v[i].y * FPSCALE));
        }
    }
    __syncthreads();
    int f = tid & 15;
    int gid = tid >> 4;   // 0..63
    int nn = N - base; if (nn > NPB) nn = NPB;
    for (int n = gid; n < nn; n += 64) {
        int gn = base + n;
        float acc = (float)accI[n * D_HID + f] * FPINV
                  + __half2float(g1h[(size_t)gn * D_HID + f]);   // + self loop
        float di = dinv[gn];
        float r = fmaxf(b1[f] + di * acc, 0.f);
        float c0 = r * W2[f * N_CLS + 0];
        float c1 = r * W2[f * N_CLS + 1];
#pragma unroll
        for (int m = 8; m >= 1; m >>= 1) {
            c0 += __shfl_xor(c0, m, 64);
            c1 += __shfl_xor(c1, m, 64);
        }
        if (f == 0) g2[gn] = make_float2(di * c0, di * c1);
    }
}

// ---------------- bucket-major agg2 (Q15.16 LDS int atomics, ILP x4) + log_softmax ----------------
__global__ __launch_bounds__(512) void k_agg2b(
        const unsigned int* __restrict__ staged, const int* __restrict__ bbase,
        const float2* __restrict__ g2, const float* __restrict__ dinv,
        const float* __restrict__ b2, float2* __restrict__ out, int N) {
    __shared__ int accI[NPB * 2];   // 2 KB
    int tid = threadIdx.x, b = blockIdx.x;
    int s0 = bbase[b], cnt = bbase[b + 1] - s0;
    int base = b * NPB;
    for (int i = tid; i < NPB * 2; i += 512) accI[i] = 0;
    __syncthreads();
    for (int j0 = tid * 4; j0 < cnt; j0 += 2048) {
        int jm = cnt - j0; if (jm > 4) jm = 4;
        unsigned int p[4]; float2 t[4];
#pragma unroll
        for (int i = 0; i < 4; ++i) if (i < jm) p[i] = staged[(size_t)s0 + j0 + i];
#pragma unroll
        for (int i = 0; i < 4; ++i) if (i < jm) t[i] = g2[p[i] >> 8];
#pragma unroll
        for (int i = 0; i < 4; ++i) if (i < jm) {
            int dl = (int)(p[i] & 255);
            atomicAdd(&accI[dl * 2 + 0], __float2int_rn(t[i].x * FPSCALE));
            atomicAdd(&accI[dl * 2 + 1], __float2int_rn(t[i].y * FPSCALE));
        }
    }
    __syncthreads();
    int nn = N - base; if (nn > NPB) nn = NPB;
    for (int n = tid; n < nn; n += 512) {
        int gn = base + n;
        float2 self = g2[gn];
        float di = dinv[gn];
        float v0 = b2[0] + di * ((float)accI[n * 2 + 0] * FPINV + self.x);
        float v1 = b2[1] + di * ((float)accI[n * 2 + 1] * FPINV + self.y);
        float mx = fmaxf(v0, v1);
        float lse = mx + logf(expf(v0 - mx) + expf(v1 - mx));
        out[gn] = make_float2(v0 - lse, v1 - lse);
    }
}

// =================== fallback (round-3 atomic path, if ws too small) ===================
__global__ void fb_deg_init(unsigned int* __restrict__ deg, int n) {
    int i = blockIdx.x * blockDim.x + threadIdx.x;
    if (i < n) deg[i] = 1u;
}
template<bool I64>
__global__ void fb_deg_count(const void* __restrict__ ei, unsigned int* __restrict__ deg,
                             int E, const int* __restrict__ flags) {
    if (flags[FE] != (int)I64) return;
    int e = blockIdx.x * blockDim.x + threadIdx.x;
    if (e < E) atomicAdd(&deg[lde<I64>(ei, (size_t)E + e)], 1u);
}
__global__ void fb_dinv_inplace(float* __restrict__ dinv, int n) {
    int i = blockIdx.x * blockDim.x + threadIdx.x;
    if (i < n) {
        unsigned int u = ((const unsigned int*)dinv)[i];
        dinv[i] = rsqrtf((float)u);
    }
}
__global__ void fb_a1_init(const float* __restrict__ h1, const float* __restrict__ dinv,
                           const float* __restrict__ b1, float* __restrict__ a1, int n) {
    int tid = blockIdx.x * blockDim.x + threadIdx.x;
    if (tid >= n * D_HID) return;
    int node = tid >> 4, f = tid & 15;
    float di = dinv[node];
    a1[tid] = b1[f] + di * di * h1[tid];
}
template<bool I64>
__global__ void fb_agg1(const void* __restrict__ ei, const float* __restrict__ dinv,
                        const float* __restrict__ h1, float* __restrict__ a1,
                        int E, const int* __restrict__ flags) {
    if (flags[FE] != (int)I64) return;
    int tid = blockIdx.x * blockDim.x + threadIdx.x;
    int e = tid >> 4, f = tid & 15;
    if (e >= E) return;
    int s = lde<I64>(ei, (size_t)e);
    int d = lde<I64>(ei, (size_t)E + e);
    float norm = dinv[s] * dinv[d];
    atomicAdd(&a1[(size_t)d * D_HID + f], h1[(size_t)s * D_HID + f] * norm);
}
__global__ void fb_relu_gemm2(const float* __restrict__ a1, const float* __restrict__ W2,
                              float* __restrict__ h2, int n) {
    int node = blockIdx.x * blockDim.x + threadIdx.x;
    if (node >= n) return;
    float c0 = 0.f, c1 = 0.f;
    const float* row = a1 + (size_t)node * D_HID;
#pragma unroll
    for (int f = 0; f < D_HID; ++f) {
        float r = fmaxf(row[f], 0.f);
        c0 += r * W2[f * N_CLS + 0];
        c1 += r * W2[f * N_CLS + 1];
    }
    h2[(size_t)node * 2 + 0] = c0;
    h2[(size_t)node * 2 + 1] = c1;
}
__global__ void fb_a2_init(const float* __restrict__ h2, const float* __restrict__ dinv,
                           const float* __restrict__ b2, float* __restrict__ a2, int n) {
    int tid = blockIdx.x * blockDim.x + threadIdx.x;
    if (tid >= n * N_CLS) return;
    int node = tid >> 1, c = tid & 1;
    float di = dinv[node];
    a2[tid] = b2[c] + di * di * h2[tid];
}
template<bool I64>
__global__ void fb_agg2(const void* __restrict__ ei, const float* __restrict__ dinv,
                        const float* __restrict__ h2, float* __restrict__ a2,
                        int E, const int* __restrict__ flags) {
    if (flags[FE] != (int)I64) return;
    int e = blockIdx.x * blockDim.x + threadIdx.x;
    if (e >= E) return;
    int s = lde<I64>(ei, (size_t)e);
    int d = lde<I64>(ei, (size_t)E + e);
    float norm = dinv[s] * dinv[d];
    atomicAdd(&a2[(size_t)d * 2 + 0], h2[(size_t)s * 2 + 0] * norm);
    atomicAdd(&a2[(size_t)d * 2 + 1], h2[(size_t)s * 2 + 1] * norm);
}
__global__ void fb_gemm1(const float* __restrict__ x, const float* __restrict__ W1,
                         float* __restrict__ h1, int n) {
    __shared__ float w[D_IN * D_HID];
    for (int i = threadIdx.x; i < D_IN * D_HID; i += blockDim.x) w[i] = W1[i];
    __syncthreads();
    int tid = blockIdx.x * blockDim.x + threadIdx.x;
    int node = tid >> 4, f = tid & 15;
    if (node >= n) return;
    const float4* xr = (const float4*)(x + (size_t)node * D_IN);
    float acc = 0.f;
#pragma unroll
    for (int k4 = 0; k4 < D_IN / 4; ++k4) {
        float4 v = xr[k4];
        int k = k4 * 4;
        acc += v.x * w[(k + 0) * D_HID + f];
        acc += v.y * w[(k + 1) * D_HID + f];
        acc += v.z * w[(k + 2) * D_HID + f];
        acc += v.w * w[(k + 3) * D_HID + f];
    }
    h1[tid] = acc;
}
__global__ void fb_lsm(const float* __restrict__ a2, float* __restrict__ out, int n) {
    int node = blockIdx.x * blockDim.x + threadIdx.x;
    if (node >= n) return;
    float v0 = a2[(size_t)node * 2 + 0];
    float v1 = a2[(size_t)node * 2 + 1];
    float m = fmaxf(v0, v1);
    float lse = m + logf(expf(v0 - m) + expf(v1 - m));
    out[(size_t)node * 2 + 0] = v0 - lse;
    out[(size_t)node * 2 + 1] = v1 - lse;
}

extern "C" void kernel_launch(void* const* d_in, const int* in_sizes, int n_in,
                              void* d_out, int out_size, void* d_ws, size_t ws_size,
                              hipStream_t stream) {
    const float* x  = (const float*)d_in[0];
    const void*  ei = d_in[1];
    const float* W1 = (const float*)d_in[2];
    const float* b1 = (const float*)d_in[3];
    const float* W2 = (const float*)d_in[4];
    const float* b2 = (const float*)d_in[5];

    const int N = in_sizes[0] / D_IN;      // 100000
    const int E = in_sizes[1] / 2;         // 3200000
    const int nb = (N + NPB - 1) / NPB;    // 391

    const int B = 256;
    dim3 blk(B);
    const int nBlkN = (N + B - 1) / B;
    const int nBlkE = (E + B - 1) / B;
    char* ws = (char*)d_ws;

    // ---- workspace layout (bytes) ----
    const size_t oDinv  = 0;                                   // N f32
    const size_t oGBcnt = (size_t)N * 4;                       // nb u32
    const size_t oBB    = oGBcnt + (size_t)nb * 4;             // (nb+1) int
    const size_t oGcur  = oBB + (size_t)(nb + 1) * 4;          // nb u32
    const size_t oFlag  = oGcur + (size_t)nb * 4;              // 2 int
    const size_t oStage = (oFlag + 8 + 63) & ~(size_t)63;      // E u32
    const size_t oG1h   = oStage + (size_t)E * 4;              // N*16 half
    const size_t oG2    = oG1h + (size_t)N * D_HID * 2;        // N*2 f32
    const size_t needNew = oG2 + (size_t)N * 2 * 4;            // ~17.3 MB

    if (ws_size >= needNew && nb <= MAXB) {
        float*        dinv   = (float*)(ws + oDinv);
        unsigned int* gbcnt  = (unsigned int*)(ws + oGBcnt);
        int*          bbase  = (int*)(ws + oBB);
        unsigned int* gcur   = (unsigned int*)(ws + oGcur);
        int*          flags  = (int*)(ws + oFlag);
        unsigned int* staged = (unsigned int*)(ws + oStage);
        __half*       g1h    = (__half*)(ws + oG1h);
        float2*       g2     = (float2*)(ws + oG2);

        k_detect<<<dim3(1), blk, 0, stream>>>((const int*)ei, flags);
        hipMemsetAsync(gbcnt, 0, (size_t)nb * 4, stream);

        k_bhist<<<dim3(256), blk, 0, stream>>>(ei, gbcnt, E, flags);
        k_bscan<<<dim3(1), dim3(MAXB), 0, stream>>>(gbcnt, bbase, gcur, nb);

        dim3 gPart((E + TILE - 1) / TILE);
        k_part<<<gPart, dim3(512), 0, stream>>>(ei, gcur, staged, E, flags);

        k_dinv2<<<dim3(nb), dim3(512), 0, stream>>>(staged, bbase, dinv, N);

        k_gemm1x<<<dim3((N + 63) / 64), dim3(256), 0, stream>>>(x, W1, dinv, g1h, N);
        k_agg1b<<<dim3(nb), dim3(1024), 0, stream>>>(staged, bbase, g1h, dinv, b1, W2, g2, N);
        k_agg2b<<<dim3(nb), dim3(512), 0, stream>>>(staged, bbase, g2, dinv, b2,
                                                    (float2*)d_out, N);
    } else {
        // fallback: round-3 atomic path (needs ~14.8 MB)
        float* dinv  = (float*)(ws + 0);
        float* h1    = (float*)(ws + 400128);
        float* a1    = (float*)(ws + 6800256);
        float* h2    = (float*)(ws + 13200384);
        float* a2    = (float*)(ws + 14000512);
        int*   flags = (int*)  (ws + 14800640);

        k_detect<<<dim3(1), blk, 0, stream>>>((const int*)ei, flags);
        fb_deg_init<<<dim3(nBlkN), blk, 0, stream>>>((unsigned int*)dinv, N);
        fb_deg_count<false><<<dim3(nBlkE), blk, 0, stream>>>(ei, (unsigned int*)dinv, E, flags);
        fb_deg_count<true ><<<dim3(nBlkE), blk, 0, stream>>>(ei, (unsigned int*)dinv, E, flags);
        fb_dinv_inplace<<<dim3(nBlkN), blk, 0, stream>>>(dinv, N);

        dim3 g_nh((N * D_HID + B - 1) / B);
        fb_gemm1<<<g_nh, blk, 0, stream>>>(x, W1, h1, N);
        fb_a1_init<<<g_nh, blk, 0, stream>>>(h1, dinv, b1, a1, N);
        dim3 g_eh(((size_t)E * D_HID + B - 1) / B);
        fb_agg1<false><<<g_eh, blk, 0, stream>>>(ei, dinv, h1, a1, E, flags);
        fb_agg1<true ><<<g_eh, blk, 0, stream>>>(ei, dinv, h1, a1, E, flags);
        fb_relu_gemm2<<<dim3(nBlkN), blk, 0, stream>>>(a1, W2, h2, N);
        dim3 g_n2((N * N_CLS + B - 1) / B);
        fb_a2_init<<<g_n2, blk, 0, stream>>>(h2, dinv, b2, a2, N);
        fb_agg2<false><<<dim3(nBlkE), blk, 0, stream>>>(ei, dinv, h2, a2, E, flags);
        fb_agg2<true ><<<dim3(nBlkE), blk, 0, stream>>>(ei, dinv, h2, a2, E, flags);
        fb_lsm<<<dim3(nBlkN), blk, 0, stream>>>(a2, (float*)d_out, N);
    }
}

// Round 13
// 223.347 us; speedup vs baseline: 2.5602x; 1.0680x over previous
//
#include <hip/hip_runtime.h>
#include <hip/hip_bf16.h>
#include <hip/hip_fp16.h>

#define D_IN  128
#define D_HID 16
#define N_CLS 2
#define NPB   256          // nodes per bucket (bucket = dst >> 8)
#define MAXB  512          // max buckets (N <= 131072)
#define TILE  8192         // edges per k_part workgroup
#define FPSCALE 65536.0f   // Q15.16 fixed-point scale for LDS int accumulation
#define FPINV   (1.0f / 65536.0f)
#define XROW  136          // padded LDS row stride (shorts): 272B, 16B-aligned, 2-way banks

#define FE 0   // edge_index storage: 0 = int32, 1 = int64

typedef short bf16x8 __attribute__((ext_vector_type(8)));
typedef float f32x4  __attribute__((ext_vector_type(4)));

__device__ __forceinline__ unsigned short f2bf(float f) {   // RNE float->bf16
    unsigned int u = __float_as_uint(f);
    u += 0x7FFFu + ((u >> 16) & 1u);
    return (unsigned short)(u >> 16);
}

// ---------------- edge dtype detection (1 block) ----------------
__global__ void k_detect(const int* __restrict__ ev, int* __restrict__ flags) {
    __shared__ int sE;
    if (threadIdx.x == 0) sE = 0;
    __syncthreads();
    if (ev[2 * threadIdx.x + 1] != 0) atomicOr(&sE, 1);
    __syncthreads();
    if (threadIdx.x == 0) flags[FE] = sE ? 0 : 1;
}

template<bool I64>
__device__ __forceinline__ int lde(const void* p, size_t i) {
    if constexpr (I64) return (int)((const long long*)p)[i];
    else               return ((const int*)p)[i];
}

// ---------------- bucket histogram (LDS-privatized, grid-stride, runtime dtype) ----------------
__global__ void k_bhist(const void* __restrict__ ei, unsigned int* __restrict__ gbcnt,
                        int E, const int* __restrict__ flags) {
    __shared__ unsigned int h[MAXB];
    for (int i = threadIdx.x; i < MAXB; i += blockDim.x) h[i] = 0u;
    __syncthreads();
    int stride = gridDim.x * blockDim.x;
    if (flags[FE]) {
        for (int e = blockIdx.x * blockDim.x + threadIdx.x; e < E; e += stride)
            atomicAdd(&h[lde<true>(ei, (size_t)E + e) >> 8], 1u);
    } else {
        for (int e = blockIdx.x * blockDim.x + threadIdx.x; e < E; e += stride)
            atomicAdd(&h[lde<false>(ei, (size_t)E + e) >> 8], 1u);
    }
    __syncthreads();
    for (int i = threadIdx.x; i < MAXB; i += blockDim.x)
        if (h[i]) atomicAdd(&gbcnt[i], h[i]);
}

// ---------------- bucket scan: bbase (exclusive) + cursor init ----------------
__global__ void k_bscan(const unsigned int* __restrict__ gbcnt, int* __restrict__ bbase,
                        unsigned int* __restrict__ gcur, int nb) {
    __shared__ int s[MAXB];
    int tid = threadIdx.x;
    int v = (tid < nb) ? (int)gbcnt[tid] : 0;
    s[tid] = v;
    __syncthreads();
#pragma unroll
    for (int off = 1; off < MAXB; off <<= 1) {
        int t = (tid >= off) ? s[tid - off] : 0;
        __syncthreads();
        s[tid] += t;
        __syncthreads();
    }
    int excl = s[tid] - v;
    if (tid <= nb) bbase[tid] = (tid < nb) ? excl : s[nb - 1];  // bbase[nb] = total
    if (tid < nb)  gcur[tid] = (unsigned int)excl;
}

// ---------------- pass 1: LDS-staged partition by bucket (runtime dtype) ----------------
template<bool I64>
__device__ __forceinline__ void part_body(
        const void* __restrict__ ei, unsigned int* __restrict__ gcur,
        unsigned int* __restrict__ staged, int E,
        unsigned int* sbuf, unsigned short* bbuf,
        int* hist, int* scn, int* lbase, int* gb) {
    int tid = threadIdx.x;
    int t0 = blockIdx.x * TILE;

    hist[tid] = 0;
    __syncthreads();

    int myB[16]; unsigned int myP[16]; int myR[16];
#pragma unroll
    for (int k = 0; k < 16; ++k) {
        int e = t0 + k * 512 + tid;
        if (e < E) {
            int s = lde<I64>(ei, (size_t)e);
            int d = lde<I64>(ei, (size_t)E + e);
            int b = d >> 8;
            myB[k] = b;
            myP[k] = ((unsigned int)s << 8) | (unsigned int)(d & 255);
            myR[k] = atomicAdd(&hist[b], 1);
        } else myB[k] = -1;
    }
    __syncthreads();

    int v = hist[tid];
    scn[tid] = v;
    __syncthreads();
#pragma unroll
    for (int off = 1; off < MAXB; off <<= 1) {
        int t = (tid >= off) ? scn[tid - off] : 0;
        __syncthreads();
        scn[tid] += t;
        __syncthreads();
    }
    int excl = scn[tid] - v;
    lbase[tid] = excl;
    int gb_ = 0;
    if (v > 0) gb_ = (int)atomicAdd(&gcur[tid], (unsigned int)v);
    gb[tid] = gb_;
    __syncthreads();

#pragma unroll
    for (int k = 0; k < 16; ++k) {
        if (myB[k] >= 0) {
            int pos = lbase[myB[k]] + myR[k];
            sbuf[pos] = myP[k];
            bbuf[pos] = (unsigned short)myB[k];
        }
    }
    __syncthreads();

    int tot = scn[MAXB - 1];
    for (int i = tid; i < tot; i += 512) {
        int b = bbuf[i];
        staged[(size_t)gb[b] + (i - lbase[b])] = sbuf[i];  // ~84B contiguous runs
    }
}

__global__ __launch_bounds__(512) void k_part(
        const void* __restrict__ ei, unsigned int* __restrict__ gcur,
        unsigned int* __restrict__ staged, int E, const int* __restrict__ flags) {
    __shared__ unsigned int sbuf[TILE];       // 32 KB
    __shared__ unsigned short bbuf[TILE];     // 16 KB
    __shared__ int hist[MAXB], scn[MAXB], lbase[MAXB], gb[MAXB];  // 8 KB
    if (flags[FE]) part_body<true >(ei, gcur, staged, E, sbuf, bbuf, hist, scn, lbase, gb);
    else           part_body<false>(ei, gcur, staged, E, sbuf, bbuf, hist, scn, lbase, gb);
}

// ---------------- per-bucket degree -> dinv (ILP x8) ----------------
__global__ __launch_bounds__(512) void k_dinv2(
        const unsigned int* __restrict__ staged, const int* __restrict__ bbase,
        float* __restrict__ dinv, int N) {
    __shared__ unsigned int h[NPB];
    int tid = threadIdx.x, b = blockIdx.x;
    int s0 = bbase[b], cnt = bbase[b + 1] - s0;
    if (tid < NPB) h[tid] = 0u;
    __syncthreads();
    for (int j0 = tid * 8; j0 < cnt; j0 += 4096) {
        int jm = cnt - j0; if (jm > 8) jm = 8;
        unsigned int p[8];
#pragma unroll
        for (int i = 0; i < 8; ++i) if (i < jm) p[i] = staged[(size_t)s0 + j0 + i];
#pragma unroll
        for (int i = 0; i < 8; ++i) if (i < jm) atomicAdd(&h[p[i] & 255], 1u);
    }
    __syncthreads();
    int base = b * NPB, nn = N - base; if (nn > NPB) nn = NPB;
    if (tid < nn) dinv[base + tid] = rsqrtf((float)(h[tid] + 1u));  // +1 self loop
}

// ---------------- layer 1 GEMM via MFMA (split-bf16, 3 mfma/chunk ~ fp32 acc) ----------------
// Block: 256 thr = 4 waves, 64 nodes. x staged once (coalesced) as bf16 hi+lo in LDS.
__global__ __launch_bounds__(256) void k_gemm1m(
        const float* __restrict__ x, const float* __restrict__ W1,
        const float* __restrict__ dinv, __half* __restrict__ g1h, int n) {
    __shared__ short xhi[64 * XROW];   // 17.4 KB
    __shared__ short xlo[64 * XROW];   // 17.4 KB
    __shared__ short whi[16 * XROW];   // 4.35 KB
    __shared__ short wlo[16 * XROW];   // 4.35 KB
    int tid = threadIdx.x;
    int node0 = blockIdx.x * 64;

    // stage W1 (128x16) transposed -> [f][k], split hi/lo
    for (int i = tid; i < D_IN * D_HID; i += 256) {
        int k = i >> 4, f = i & 15;
        float v = W1[i];
        unsigned short h = f2bf(v);
        float fh = __uint_as_float(((unsigned int)h) << 16);
        whi[f * XROW + k] = (short)h;
        wlo[f * XROW + k] = (short)f2bf(v - fh);
    }
    // stage x tile (64 rows x 128), coalesced float4, split hi/lo
    int limFlat = (n - node0) * D_IN;   // valid floats in tile
#pragma unroll
    for (int it = 0; it < 8; ++it) {
        int flat = it * 1024 + tid * 4;
        float4 v = make_float4(0.f, 0.f, 0.f, 0.f);
        if (flat < limFlat) v = *(const float4*)(x + (size_t)node0 * D_IN + flat);
        int row = flat >> 7, k = flat & 127;
        unsigned short h0 = f2bf(v.x), h1 = f2bf(v.y), h2 = f2bf(v.z), h3 = f2bf(v.w);
        unsigned short l0 = f2bf(v.x - __uint_as_float(((unsigned int)h0) << 16));
        unsigned short l1 = f2bf(v.y - __uint_as_float(((unsigned int)h1) << 16));
        unsigned short l2 = f2bf(v.z - __uint_as_float(((unsigned int)h2) << 16));
        unsigned short l3 = f2bf(v.w - __uint_as_float(((unsigned int)h3) << 16));
        int o = row * XROW + k;
        *(uint2*)(&xhi[o]) = make_uint2((unsigned int)h0 | ((unsigned int)h1 << 16),
                                        (unsigned int)h2 | ((unsigned int)h3 << 16));
        *(uint2*)(&xlo[o]) = make_uint2((unsigned int)l0 | ((unsigned int)l1 << 16),
                                        (unsigned int)l2 | ((unsigned int)l3 << 16));
    }
    __syncthreads();

    int w = tid >> 6, L = tid & 63;
    int m = L & 15, q = L >> 4;
    const short* axh = &xhi[(w * 16 + m) * XROW + q * 8];
    const short* axl = &xlo[(w * 16 + m) * XROW + q * 8];
    const short* bwh = &whi[m * XROW + q * 8];       // n-index = lane&15
    const short* bwl = &wlo[m * XROW + q * 8];
    f32x4 acc = {0.f, 0.f, 0.f, 0.f};
#pragma unroll
    for (int c = 0; c < 4; ++c) {
        bf16x8 ah = *(const bf16x8*)(axh + c * 32);
        bf16x8 al = *(const bf16x8*)(axl + c * 32);
        bf16x8 bh = *(const bf16x8*)(bwh + c * 32);
        bf16x8 bl = *(const bf16x8*)(bwl + c * 32);
        acc = __builtin_amdgcn_mfma_f32_16x16x32_bf16(ah, bh, acc, 0, 0, 0);
        acc = __builtin_amdgcn_mfma_f32_16x16x32_bf16(ah, bl, acc, 0, 0, 0);
        acc = __builtin_amdgcn_mfma_f32_16x16x32_bf16(al, bh, acc, 0, 0, 0);
    }
    // D layout: row = q*4 + reg (node offset), col = lane&15 (f)
    int nodeB = node0 + w * 16 + q * 4;
#pragma unroll
    for (int r = 0; r < 4; ++r) {
        int node = nodeB + r;
        if (node < n) g1h[(size_t)node * D_HID + m] = __float2half(dinv[node] * acc[r]);
    }
}

// ---------------- bucket-major agg1 (Q15.16 LDS int atomics, half2, ILP x8) ----------------
__global__ __launch_bounds__(1024) void k_agg1b(
        const unsigned int* __restrict__ staged, const int* __restrict__ bbase,
        const __half* __restrict__ g1h, const float* __restrict__ dinv,
        const float* __restrict__ b1, const float* __restrict__ W2,
        float2* __restrict__ g2, int N) {
    __shared__ int accI[NPB * D_HID];   // 16 KB
    int tid = threadIdx.x, b = blockIdx.x;
    int s0 = bbase[b], cnt = bbase[b + 1] - s0;
    int base = b * NPB;
    for (int i = tid; i < NPB * D_HID; i += 1024) accI[i] = 0;
    __syncthreads();
    const __half2* g1h2 = (const __half2*)g1h;
    int f2 = tid & 7;          // feature pair 0..7
    int eg = tid >> 3;         // edge group 0..127
    for (int j0 = eg * 8; j0 < cnt; j0 += 1024) {
        int jm = cnt - j0; if (jm > 8) jm = 8;
        unsigned int p[8]; float2 v[8];
#pragma unroll
        for (int i = 0; i < 8; ++i) if (i < jm) p[i] = staged[(size_t)s0 + j0 + i];
#pragma unroll
        for (int i = 0; i < 8; ++i) if (i < jm)
            v[i] = __half22float2(g1h2[(size_t)(p[i] >> 8) * 8 + f2]);
#pragma unroll
        for (int i = 0; i < 8; ++i) if (i < jm) {
            int a = (int)(p[i] & 255) * D_HID + f2 * 2;
            atomicAdd(&accI[a + 0], __float2int_rn(v[i].x * FPSCALE));
            atomicAdd(&accI[a + 1], __float2int_rn(v[i].y * FPSCALE));
        }
    }
    __syncthreads();
    int f = tid & 15;
    int gid = tid >> 4;   // 0..63
    int nn = N - base; if (nn > NPB) nn = NPB;
    for (int n = gid; n < nn; n += 64) {
        int gn = base + n;
        float acc = (float)accI[n * D_HID + f] * FPINV
                  + __half2float(g1h[(size_t)gn * D_HID + f]);   // + self loop
        float di = dinv[gn];
        float r = fmaxf(b1[f] + di * acc, 0.f);
        float c0 = r * W2[f * N_CLS + 0];
        float c1 = r * W2[f * N_CLS + 1];
#pragma unroll
        for (int m = 8; m >= 1; m >>= 1) {
            c0 += __shfl_xor(c0, m, 64);
            c1 += __shfl_xor(c1, m, 64);
        }
        if (f == 0) g2[gn] = make_float2(di * c0, di * c1);
    }
}

// ---------------- bucket-major agg2 (Q15.16 LDS int atomics, ILP x4) + log_softmax ----------------
__global__ __launch_bounds__(512) void k_agg2b(
        const unsigned int* __restrict__ staged, const int* __restrict__ bbase,
        const float2* __restrict__ g2, const float* __restrict__ dinv,
        const float* __restrict__ b2, float2* __restrict__ out, int N) {
    __shared__ int accI[NPB * 2];   // 2 KB
    int tid = threadIdx.x, b = blockIdx.x;
    int s0 = bbase[b], cnt = bbase[b + 1] - s0;
    int base = b * NPB;
    for (int i = tid; i < NPB * 2; i += 512) accI[i] = 0;
    __syncthreads();
    for (int j0 = tid * 4; j0 < cnt; j0 += 2048) {
        int jm = cnt - j0; if (jm > 4) jm = 4;
        unsigned int p[4]; float2 t[4];
#pragma unroll
        for (int i = 0; i < 4; ++i) if (i < jm) p[i] = staged[(size_t)s0 + j0 + i];
#pragma unroll
        for (int i = 0; i < 4; ++i) if (i < jm) t[i] = g2[p[i] >> 8];
#pragma unroll
        for (int i = 0; i < 4; ++i) if (i < jm) {
            int dl = (int)(p[i] & 255);
            atomicAdd(&accI[dl * 2 + 0], __float2int_rn(t[i].x * FPSCALE));
            atomicAdd(&accI[dl * 2 + 1], __float2int_rn(t[i].y * FPSCALE));
        }
    }
    __syncthreads();
    int nn = N - base; if (nn > NPB) nn = NPB;
    for (int n = tid; n < nn; n += 512) {
        int gn = base + n;
        float2 self = g2[gn];
        float di = dinv[gn];
        float v0 = b2[0] + di * ((float)accI[n * 2 + 0] * FPINV + self.x);
        float v1 = b2[1] + di * ((float)accI[n * 2 + 1] * FPINV + self.y);
        float mx = fmaxf(v0, v1);
        float lse = mx + logf(expf(v0 - mx) + expf(v1 - mx));
        out[gn] = make_float2(v0 - lse, v1 - lse);
    }
}

// =================== fallback (round-3 atomic path, if ws too small) ===================
__global__ void fb_deg_init(unsigned int* __restrict__ deg, int n) {
    int i = blockIdx.x * blockDim.x + threadIdx.x;
    if (i < n) deg[i] = 1u;
}
template<bool I64>
__global__ void fb_deg_count(const void* __restrict__ ei, unsigned int* __restrict__ deg,
                             int E, const int* __restrict__ flags) {
    if (flags[FE] != (int)I64) return;
    int e = blockIdx.x * blockDim.x + threadIdx.x;
    if (e < E) atomicAdd(&deg[lde<I64>(ei, (size_t)E + e)], 1u);
}
__global__ void fb_dinv_inplace(float* __restrict__ dinv, int n) {
    int i = blockIdx.x * blockDim.x + threadIdx.x;
    if (i < n) {
        unsigned int u = ((const unsigned int*)dinv)[i];
        dinv[i] = rsqrtf((float)u);
    }
}
__global__ void fb_a1_init(const float* __restrict__ h1, const float* __restrict__ dinv,
                           const float* __restrict__ b1, float* __restrict__ a1, int n) {
    int tid = blockIdx.x * blockDim.x + threadIdx.x;
    if (tid >= n * D_HID) return;
    int node = tid >> 4, f = tid & 15;
    float di = dinv[node];
    a1[tid] = b1[f] + di * di * h1[tid];
}
template<bool I64>
__global__ void fb_agg1(const void* __restrict__ ei, const float* __restrict__ dinv,
                        const float* __restrict__ h1, float* __restrict__ a1,
                        int E, const int* __restrict__ flags) {
    if (flags[FE] != (int)I64) return;
    int tid = blockIdx.x * blockDim.x + threadIdx.x;
    int e = tid >> 4, f = tid & 15;
    if (e >= E) return;
    int s = lde<I64>(ei, (size_t)e);
    int d = lde<I64>(ei, (size_t)E + e);
    float norm = dinv[s] * dinv[d];
    atomicAdd(&a1[(size_t)d * D_HID + f], h1[(size_t)s * D_HID + f] * norm);
}
__global__ void fb_relu_gemm2(const float* __restrict__ a1, const float* __restrict__ W2,
                              float* __restrict__ h2, int n) {
    int node = blockIdx.x * blockDim.x + threadIdx.x;
    if (node >= n) return;
    float c0 = 0.f, c1 = 0.f;
    const float* row = a1 + (size_t)node * D_HID;
#pragma unroll
    for (int f = 0; f < D_HID; ++f) {
        float r = fmaxf(row[f], 0.f);
        c0 += r * W2[f * N_CLS + 0];
        c1 += r * W2[f * N_CLS + 1];
    }
    h2[(size_t)node * 2 + 0] = c0;
    h2[(size_t)node * 2 + 1] = c1;
}
__global__ void fb_a2_init(const float* __restrict__ h2, const float* __restrict__ dinv,
                           const float* __restrict__ b2, float* __restrict__ a2, int n) {
    int tid = blockIdx.x * blockDim.x + threadIdx.x;
    if (tid >= n * N_CLS) return;
    int node = tid >> 1, c = tid & 1;
    float di = dinv[node];
    a2[tid] = b2[c] + di * di * h2[tid];
}
template<bool I64>
__global__ void fb_agg2(const void* __restrict__ ei, const float* __restrict__ dinv,
                        const float* __restrict__ h2, float* __restrict__ a2,
                        int E, const int* __restrict__ flags) {
    if (flags[FE] != (int)I64) return;
    int e = blockIdx.x * blockDim.x + threadIdx.x;
    if (e >= E) return;
    int s = lde<I64>(ei, (size_t)e);
    int d = lde<I64>(ei, (size_t)E + e);
    float norm = dinv[s] * dinv[d];
    atomicAdd(&a2[(size_t)d * 2 + 0], h2[(size_t)s * 2 + 0] * norm);
    atomicAdd(&a2[(size_t)d * 2 + 1], h2[(size_t)s * 2 + 1] * norm);
}
__global__ void fb_gemm1(const float* __restrict__ x, const float* __restrict__ W1,
                         float* __restrict__ h1, int n) {
    __shared__ float w[D_IN * D_HID];
    for (int i = threadIdx.x; i < D_IN * D_HID; i += blockDim.x) w[i] = W1[i];
    __syncthreads();
    int tid = blockIdx.x * blockDim.x + threadIdx.x;
    int node = tid >> 4, f = tid & 15;
    if (node >= n) return;
    const float4* xr = (const float4*)(x + (size_t)node * D_IN);
    float acc = 0.f;
#pragma unroll
    for (int k4 = 0; k4 < D_IN / 4; ++k4) {
        float4 v = xr[k4];
        int k = k4 * 4;
        acc += v.x * w[(k + 0) * D_HID + f];
        acc += v.y * w[(k + 1) * D_HID + f];
        acc += v.z * w[(k + 2) * D_HID + f];
        acc += v.w * w[(k + 3) * D_HID + f];
    }
    h1[tid] = acc;
}
__global__ void fb_lsm(const float* __restrict__ a2, float* __restrict__ out, int n) {
    int node = blockIdx.x * blockDim.x + threadIdx.x;
    if (node >= n) return;
    float v0 = a2[(size_t)node * 2 + 0];
    float v1 = a2[(size_t)node * 2 + 1];
    float m = fmaxf(v0, v1);
    float lse = m + logf(expf(v0 - m) + expf(v1 - m));
    out[(size_t)node * 2 + 0] = v0 - lse;
    out[(size_t)node * 2 + 1] = v1 - lse;
}

extern "C" void kernel_launch(void* const* d_in, const int* in_sizes, int n_in,
                              void* d_out, int out_size, void* d_ws, size_t ws_size,
                              hipStream_t stream) {
    const float* x  = (const float*)d_in[0];
    const void*  ei = d_in[1];
    const float* W1 = (const float*)d_in[2];
    const float* b1 = (const float*)d_in[3];
    const float* W2 = (const float*)d_in[4];
    const float* b2 = (const float*)d_in[5];

    const int N = in_sizes[0] / D_IN;      // 100000
    const int E = in_sizes[1] / 2;         // 3200000
    const int nb = (N + NPB - 1) / NPB;    // 391

    const int B = 256;
    dim3 blk(B);
    const int nBlkN = (N + B - 1) / B;
    const int nBlkE = (E + B - 1) / B;
    char* ws = (char*)d_ws;

    // ---- workspace layout (bytes) ----
    const size_t oDinv  = 0;                                   // N f32
    const size_t oGBcnt = (size_t)N * 4;                       // nb u32
    const size_t oBB    = oGBcnt + (size_t)nb * 4;             // (nb+1) int
    const size_t oGcur  = oBB + (size_t)(nb + 1) * 4;          // nb u32
    const size_t oFlag  = oGcur + (size_t)nb * 4;              // 2 int
    const size_t oStage = (oFlag + 8 + 63) & ~(size_t)63;      // E u32
    const size_t oG1h   = oStage + (size_t)E * 4;              // N*16 half
    const size_t oG2    = oG1h + (size_t)N * D_HID * 2;        // N*2 f32
    const size_t needNew = oG2 + (size_t)N * 2 * 4;            // ~17.3 MB

    if (ws_size >= needNew && nb <= MAXB) {
        float*        dinv   = (float*)(ws + oDinv);
        unsigned int* gbcnt  = (unsigned int*)(ws + oGBcnt);
        int*          bbase  = (int*)(ws + oBB);
        unsigned int* gcur   = (unsigned int*)(ws + oGcur);
        int*          flags  = (int*)(ws + oFlag);
        unsigned int* staged = (unsigned int*)(ws + oStage);
        __half*       g1h    = (__half*)(ws + oG1h);
        float2*       g2     = (float2*)(ws + oG2);

        k_detect<<<dim3(1), blk, 0, stream>>>((const int*)ei, flags);
        hipMemsetAsync(gbcnt, 0, (size_t)nb * 4, stream);

        k_bhist<<<dim3(256), blk, 0, stream>>>(ei, gbcnt, E, flags);
        k_bscan<<<dim3(1), dim3(MAXB), 0, stream>>>(gbcnt, bbase, gcur, nb);

        dim3 gPart((E + TILE - 1) / TILE);
        k_part<<<gPart, dim3(512), 0, stream>>>(ei, gcur, staged, E, flags);

        k_dinv2<<<dim3(nb), dim3(512), 0, stream>>>(staged, bbase, dinv, N);

        k_gemm1m<<<dim3((N + 63) / 64), dim3(256), 0, stream>>>(x, W1, dinv, g1h, N);
        k_agg1b<<<dim3(nb), dim3(1024), 0, stream>>>(staged, bbase, g1h, dinv, b1, W2, g2, N);
        k_agg2b<<<dim3(nb), dim3(512), 0, stream>>>(staged, bbase, g2, dinv, b2,
                                                    (float2*)d_out, N);
    } else {
        // fallback: round-3 atomic path (needs ~14.8 MB)
        float* dinv  = (float*)(ws + 0);
        float* h1    = (float*)(ws + 400128);
        float* a1    = (float*)(ws + 6800256);
        float* h2    = (float*)(ws + 13200384);
        float* a2    = (float*)(ws + 14000512);
        int*   flags = (int*)  (ws + 14800640);

        k_detect<<<dim3(1), blk, 0, stream>>>((const int*)ei, flags);
        fb_deg_init<<<dim3(nBlkN), blk, 0, stream>>>((unsigned int*)dinv, N);
        fb_deg_count<false><<<dim3(nBlkE), blk, 0, stream>>>(ei, (unsigned int*)dinv, E, flags);
        fb_deg_count<true ><<<dim3(nBlkE), blk, 0, stream>>>(ei, (unsigned int*)dinv, E, flags);
        fb_dinv_inplace<<<dim3(nBlkN), blk, 0, stream>>>(dinv, N);

        dim3 g_nh((N * D_HID + B - 1) / B);
        fb_gemm1<<<g_nh, blk, 0, stream>>>(x, W1, h1, N);
        fb_a1_init<<<g_nh, blk, 0, stream>>>(h1, dinv, b1, a1, N);
        dim3 g_eh(((size_t)E * D_HID + B - 1) / B);
        fb_agg1<false><<<g_eh, blk, 0, stream>>>(ei, dinv, h1, a1, E, flags);
        fb_agg1<true ><<<g_eh, blk, 0, stream>>>(ei, dinv, h1, a1, E, flags);
        fb_relu_gemm2<<<dim3(nBlkN), blk, 0, stream>>>(a1, W2, h2, N);
        dim3 g_n2((N * N_CLS + B - 1) / B);
        fb_a2_init<<<g_n2, blk, 0, stream>>>(h2, dinv, b2, a2, N);
        fb_agg2<false><<<dim3(nBlkE), blk, 0, stream>>>(ei, dinv, h2, a2, E, flags);
        fb_agg2<true ><<<dim3(nBlkE), blk, 0, stream>>>(ei, dinv, h2, a2, E, flags);
        fb_lsm<<<dim3(nBlkN), blk, 0, stream>>>(a2, (float*)d_out, N);
    }
}